// Round 1
// baseline (1285.957 us; speedup 1.0000x reference)
//
#include <hip/hip_runtime.h>
#include <math.h>

#define E 256
#define KTOP 10

// ---------- helpers ----------
__device__ inline float wsum(float v) {
    v += __shfl_xor(v, 1, 64);
    v += __shfl_xor(v, 2, 64);
    v += __shfl_xor(v, 4, 64);
    v += __shfl_xor(v, 8, 64);
    v += __shfl_xor(v, 16, 64);
    v += __shfl_xor(v, 32, 64);
    return v;
}

__device__ inline float dot4(float4 a, float4 b) {
    return a.x * b.x + a.y * b.y + a.z * b.z + a.w * b.w;
}

__device__ inline float gk(float d) {  // Gaussian kernel on squared distance
    return expf(-0.5f * fmaxf(d, 0.0f));
}

__device__ inline void atomicMaxF(float* addr, float v) {
    // valid for non-negative floats only (uint order == float order)
    atomicMax((unsigned int*)addr, __float_as_uint(v));
}

// ---------- kernels ----------
__global__ void k_init(float* out, int B) {
    if ((int)threadIdx.x < B) out[threadIdx.x] = 0.0f;
}

// hop_rel[rh][b][:] = rel[b] @ W[rh] + bias[rh];  nhr[rh][b] = ||hop_rel||^2
__global__ void k_hoprel(const float* __restrict__ rel, const float* __restrict__ W,
                         const float* __restrict__ bias, float* __restrict__ hr,
                         float* __restrict__ nhr, int B) {
    int b = blockIdx.x, rh = blockIdx.y;
    int j = threadIdx.x;  // 0..255
    __shared__ float relS[E];
    relS[j] = rel[b * E + j];
    __syncthreads();
    const float* Wp = W + (size_t)rh * E * E;
    float acc = bias[rh * E + j];
#pragma unroll 8
    for (int e = 0; e < E; ++e) acc = fmaf(relS[e], Wp[e * E + j], acc);
    hr[((size_t)rh * B + b) * E + j] = acc;
    float s = wsum(acc * acc);
    __shared__ float red[4];
    int wave = j >> 6;
    if ((j & 63) == 0) red[wave] = s;
    __syncthreads();
    if (j == 0) nhr[rh * B + b] = red[0] + red[1] + red[2] + red[3];
}

// squared norms of rows of length E
__global__ void k_rownorm(const float* __restrict__ src, float* __restrict__ dst, int nrows) {
    int row = blockIdx.x * 4 + (threadIdx.x >> 6);
    if (row >= nrows) return;
    int lane = threadIdx.x & 63;
    float4 v = ((const float4*)(src + (size_t)row * E))[lane];
    float s = wsum(dot4(v, v));
    if (lane == 0) dst[row] = s;
}

// per-(b,f): all query-vs-fact kernels that are constant over entities.
// Produces wh1[2][B][F], wh2[2][B][F], nf1, nf2 and atomically folds scores_0 into out.
__global__ void k_pairmap(const float* __restrict__ rel, const float* __restrict__ arg1,
                          const float* __restrict__ arg2, const float* __restrict__ frel,
                          const float* __restrict__ fa1, const float* __restrict__ fa2,
                          const int* __restrict__ nbf, const float* __restrict__ hr,
                          const float* __restrict__ nhr, const float* __restrict__ nrel,
                          const float* __restrict__ na1, const float* __restrict__ na2,
                          float* __restrict__ wh1, float* __restrict__ wh2,
                          float* __restrict__ nf1, float* __restrict__ nf2,
                          float* __restrict__ out, int B, int F) {
    int b = blockIdx.y;
    int f0 = blockIdx.x * 128;
    int tid = threadIdx.x;
    __shared__ float qS[7 * E];
    __shared__ float nq[7];
    for (int i = tid; i < 7 * E; i += 256) {
        int q = i >> 8, e = i & 255;
        float v;
        if (q == 0) v = rel[b * E + e];
        else if (q == 1) v = arg1[b * E + e];
        else if (q == 2) v = arg2[b * E + e];
        else v = hr[((size_t)(q - 3) * B + b) * E + e];
        qS[i] = v;
    }
    if (tid < 7)
        nq[tid] = (tid == 0) ? nrel[b] : (tid == 1) ? na1[b] : (tid == 2) ? na2[b]
                                                             : nhr[(tid - 3) * B + b];
    __syncthreads();
    int lane = tid & 63, wave = tid >> 6;
    const float4* q4 = (const float4*)qS;
    float4 qrel = q4[lane], qa1 = q4[64 + lane], qa2 = q4[128 + lane];
    float4 qh00 = q4[192 + lane], qh01 = q4[256 + lane], qh10 = q4[320 + lane],
           qh11 = q4[384 + lane];
    int nbfb = nbf[b];
    int fend = min(f0 + 128, F);
    for (int f = f0 + wave; f < fend; f += 4) {
        float4 v = ((const float4*)(frel + ((size_t)b * F + f) * E))[lane];
        float d_rel = dot4(v, qrel), d_h00 = dot4(v, qh00), d_h01 = dot4(v, qh01);
        float d_h10 = dot4(v, qh10), d_h11 = dot4(v, qh11), n_fr = dot4(v, v);
        float4 v1 = ((const float4*)(fa1 + ((size_t)b * F + f) * E))[lane];
        float d_a1f1 = dot4(v1, qa1), d_a2f1 = dot4(v1, qa2), n_f1 = dot4(v1, v1);
        float4 v2 = ((const float4*)(fa2 + ((size_t)b * F + f) * E))[lane];
        float d_a1f2 = dot4(v2, qa1), d_a2f2 = dot4(v2, qa2), n_f2 = dot4(v2, v2);
        d_rel = wsum(d_rel); d_h00 = wsum(d_h00); d_h01 = wsum(d_h01);
        d_h10 = wsum(d_h10); d_h11 = wsum(d_h11); n_fr = wsum(n_fr);
        d_a1f1 = wsum(d_a1f1); d_a2f1 = wsum(d_a2f1); n_f1 = wsum(n_f1);
        d_a1f2 = wsum(d_a1f2); d_a2f2 = wsum(d_a2f2); n_f2 = wsum(n_f2);
        if (lane == 0) {
            float m = (f < nbfb) ? 1.0f : 0.0f;
            float krel = gk(nq[0] + n_fr - 2.f * d_rel);
            float kh00 = gk(nq[3] + n_fr - 2.f * d_h00);
            float kh01 = gk(nq[4] + n_fr - 2.f * d_h01);
            float kh10 = gk(nq[5] + n_fr - 2.f * d_h10);
            float kh11 = gk(nq[6] + n_fr - 2.f * d_h11);
            float ka1f1 = gk(nq[1] + n_f1 - 2.f * d_a1f1);
            float ka2f1 = gk(nq[2] + n_f1 - 2.f * d_a2f1);
            float ka1f2 = gk(nq[1] + n_f2 - 2.f * d_a1f2);
            float ka2f2 = gk(nq[2] + n_f2 - 2.f * d_a2f2);
            size_t bf = (size_t)b * F + f;
            nf1[bf] = n_f1;
            nf2[bf] = n_f2;
            wh1[bf] = kh00 * ka1f1 * m;                   // rule0 hop1 const part
            wh1[(size_t)B * F + bf] = kh10 * ka1f2 * m;   // rule1 hop1 const part
            wh2[bf] = kh01 * ka2f2 * m;                   // rule0 hop2 const part
            wh2[(size_t)B * F + bf] = kh11 * ka2f1 * m;   // rule1 hop2 const part
            atomicMaxF(&out[b], krel * ka1f1 * ka2f2 * m);  // scores_0
        }
    }
}

// hop1: nsc[r][b][n] = max_f wh1[r][b][f] * exp(-0.5*relu(ne[n]+nf[f]-2*ent[n].fact[f]))
#define TN 64
#define TF 64
#define TK 16
#define TPAD 4
__global__ __launch_bounds__(256) void k_hop1(
    const float* __restrict__ ent, const float* __restrict__ fa1,
    const float* __restrict__ fa2, const float* __restrict__ nf1,
    const float* __restrict__ nf2, const float* __restrict__ ne,
    const float* __restrict__ wh1, float* __restrict__ nsc, int B, int N, int F) {
    int r = blockIdx.z, b = blockIdx.y, n0 = blockIdx.x * TN;
    const float* fact = (r == 0) ? fa2 : fa1;
    const float* nf = (r == 0) ? nf2 : nf1;
    const float* w = wh1 + (size_t)r * B * F;
    __shared__ float eT[TK][TN + TPAD];
    __shared__ float fT[TK][TF + TPAD];
    int tid = threadIdx.x;
    int ty = tid >> 4, tx = tid & 15;
    int lr = tid >> 2;           // 0..63 (row within tile for staging loads)
    int lc = (tid & 3) * 4;      // 0,4,8,12 (col within K-slice)
    float nei[4];
#pragma unroll
    for (int i = 0; i < 4; ++i) nei[i] = ne[(size_t)b * N + n0 + ty * 4 + i];
    float mx[4] = {0.f, 0.f, 0.f, 0.f};
    for (int f0 = 0; f0 < F; f0 += TF) {
        float acc[4][4];
#pragma unroll
        for (int i = 0; i < 4; ++i)
#pragma unroll
            for (int j = 0; j < 4; ++j) acc[i][j] = 0.f;
        for (int k0 = 0; k0 < E; k0 += TK) {
            float4 ev = *(const float4*)(ent + ((size_t)b * N + n0 + lr) * E + k0 + lc);
            float4 fv = *(const float4*)(fact + ((size_t)b * F + f0 + lr) * E + k0 + lc);
            __syncthreads();  // protect previous iteration's reads
            eT[lc + 0][lr] = ev.x; eT[lc + 1][lr] = ev.y;
            eT[lc + 2][lr] = ev.z; eT[lc + 3][lr] = ev.w;
            fT[lc + 0][lr] = fv.x; fT[lc + 1][lr] = fv.y;
            fT[lc + 2][lr] = fv.z; fT[lc + 3][lr] = fv.w;
            __syncthreads();
#pragma unroll
            for (int kk = 0; kk < TK; ++kk) {
                float4 a = *(const float4*)&eT[kk][ty * 4];
                float4 bb = *(const float4*)&fT[kk][tx * 4];
                float av[4] = {a.x, a.y, a.z, a.w};
                float bv[4] = {bb.x, bb.y, bb.z, bb.w};
#pragma unroll
                for (int i = 0; i < 4; ++i)
#pragma unroll
                    for (int j = 0; j < 4; ++j) acc[i][j] = fmaf(av[i], bv[j], acc[i][j]);
            }
        }
#pragma unroll
        for (int j = 0; j < 4; ++j) {
            int f = f0 + tx * 4 + j;
            float wf = w[(size_t)b * F + f];
            float nff = nf[(size_t)b * F + f];
#pragma unroll
            for (int i = 0; i < 4; ++i) {
                float d = nei[i] + nff - 2.f * acc[i][j];
                float v = wf * expf(-0.5f * fmaxf(d, 0.f));
                mx[i] = fmaxf(mx[i], v);
            }
        }
    }
#pragma unroll
    for (int i = 0; i < 4; ++i) {
        float v = mx[i];
        v = fmaxf(v, __shfl_xor(v, 1, 64));
        v = fmaxf(v, __shfl_xor(v, 2, 64));
        v = fmaxf(v, __shfl_xor(v, 4, 64));
        v = fmaxf(v, __shfl_xor(v, 8, 64));
        if (tx == 0) nsc[((size_t)r * B + b) * N + n0 + ty * 4 + i] = v;
    }
}

// top-10 per (r,b) with jax.lax.top_k tie-breaking (lower index wins on equal value)
__global__ void k_topk(const float* __restrict__ nsc, float* __restrict__ zval,
                       int* __restrict__ zidx, int B, int N) {
    int b = blockIdx.x, r = blockIdx.y;
    int tid = threadIdx.x;
    extern __shared__ float sv[];  // N floats
    const float* src = nsc + ((size_t)r * B + b) * N;
    for (int i = tid; i < N; i += 256) sv[i] = src[i];
    __syncthreads();
    __shared__ float rv[256];
    __shared__ int ri[256];
    for (int t = 0; t < KTOP; ++t) {
        float bv = -1.f;
        int bi = 0;
        for (int i = tid; i < N; i += 256) {
            float v = sv[i];
            if (v > bv || (v == bv && i < bi)) { bv = v; bi = i; }
        }
        rv[tid] = bv; ri[tid] = bi;
        __syncthreads();
        for (int s = 128; s > 0; s >>= 1) {
            if (tid < s) {
                float v2 = rv[tid + s]; int i2 = ri[tid + s];
                if (v2 > rv[tid] || (v2 == rv[tid] && i2 < ri[tid])) {
                    rv[tid] = v2; ri[tid] = i2;
                }
            }
            __syncthreads();
        }
        if (tid == 0) {
            zval[((size_t)r * B + b) * KTOP + t] = rv[0];
            zidx[((size_t)r * B + b) * KTOP + t] = ri[0];
            sv[ri[0]] = -2.f;  // remove; all real values are >= 0
        }
        __syncthreads();
    }
}

// hop2 for the 10 selected sources per (r,b); fold min(hop2, hop1) max into out.
__global__ void k_hop2(const float* __restrict__ ent, const float* __restrict__ fa1,
                       const float* __restrict__ fa2, const float* __restrict__ nf1,
                       const float* __restrict__ nf2, const float* __restrict__ ne,
                       const float* __restrict__ wh2, const float* __restrict__ zval,
                       const int* __restrict__ zidx, float* __restrict__ out, int B,
                       int N, int F) {
    int k = blockIdx.x, b = blockIdx.y, r = blockIdx.z;
    const float* fact = (r == 0) ? fa1 : fa2;  // r0: src vs fact_arg1; r1: src vs fact_arg2
    const float* nf = (r == 0) ? nf1 : nf2;
    int tid = threadIdx.x, lane = tid & 63, wave = tid >> 6;
    int idx = zidx[((size_t)r * B + b) * KTOP + k];
    __shared__ float sS[E];
    sS[tid] = ent[((size_t)b * N + idx) * E + tid];
    __syncthreads();
    float nsrc = ne[(size_t)b * N + idx];
    float4 q = ((const float4*)sS)[lane];
    float vmax = 0.f;
    for (int f = wave; f < F; f += 4) {
        float4 v = *(const float4*)(fact + ((size_t)b * F + f) * E + lane * 4);
        float d = wsum(dot4(v, q));
        float wf = wh2[(size_t)r * B * F + (size_t)b * F + f];
        float val = wf * expf(-0.5f * fmaxf(nsrc + nf[(size_t)b * F + f] - 2.f * d, 0.f));
        vmax = fmaxf(vmax, val);
    }
    __shared__ float red[4];
    if (lane == 0) red[wave] = vmax;
    __syncthreads();
    if (tid == 0) {
        float z2 = fmaxf(fmaxf(red[0], red[1]), fmaxf(red[2], red[3]));
        float sc = fminf(z2, zval[((size_t)r * B + b) * KTOP + k]);
        atomicMaxF(&out[b], sc);
    }
}

// ---------- launcher ----------
extern "C" void kernel_launch(void* const* d_in, const int* in_sizes, int n_in,
                              void* d_out, int out_size, void* d_ws, size_t ws_size,
                              hipStream_t stream) {
    const float* rel = (const float*)d_in[0];
    const float* arg1 = (const float*)d_in[1];
    const float* arg2 = (const float*)d_in[2];
    const float* frel = (const float*)d_in[3];
    const float* fa1 = (const float*)d_in[4];
    const float* fa2 = (const float*)d_in[5];
    const int* nbf = (const int*)d_in[6];
    const float* ent = (const float*)d_in[7];
    // d_in[8] nb_entities: unused by the reference
    const float* W = (const float*)d_in[9];
    const float* bias = (const float*)d_in[10];
    int B = in_sizes[0] / E;
    int F = in_sizes[3] / (B * E);
    int N = in_sizes[7] / (B * E);
    float* out = (float*)d_out;

    float* ws = (float*)d_ws;
    size_t o = 0;
    float* hr = ws + o;   o += (size_t)4 * B * E;
    float* nhr = ws + o;  o += (size_t)4 * B;
    float* nrel = ws + o; o += B;
    float* na1 = ws + o;  o += B;
    float* na2 = ws + o;  o += B;
    float* nf1 = ws + o;  o += (size_t)B * F;
    float* nf2 = ws + o;  o += (size_t)B * F;
    float* ne_ = ws + o;  o += (size_t)B * N;
    float* wh1 = ws + o;  o += (size_t)2 * B * F;
    float* wh2 = ws + o;  o += (size_t)2 * B * F;
    float* nsc = ws + o;  o += (size_t)2 * B * N;
    float* zval = ws + o; o += (size_t)2 * B * KTOP;
    int* zidx = (int*)(ws + o);

    k_init<<<dim3(1), dim3(64), 0, stream>>>(out, B);
    k_hoprel<<<dim3(B, 4), dim3(E), 0, stream>>>(rel, W, bias, hr, nhr, B);
    k_rownorm<<<dim3((B + 3) / 4), dim3(256), 0, stream>>>(rel, nrel, B);
    k_rownorm<<<dim3((B + 3) / 4), dim3(256), 0, stream>>>(arg1, na1, B);
    k_rownorm<<<dim3((B + 3) / 4), dim3(256), 0, stream>>>(arg2, na2, B);
    k_rownorm<<<dim3((B * F + 3) / 4), dim3(256), 0, stream>>>(fa1, nf1, B * F);
    k_rownorm<<<dim3((B * F + 3) / 4), dim3(256), 0, stream>>>(fa2, nf2, B * F);
    k_rownorm<<<dim3((B * N + 3) / 4), dim3(256), 0, stream>>>(ent, ne_, B * N);
    k_pairmap<<<dim3((F + 127) / 128, B), dim3(256), 0, stream>>>(
        rel, arg1, arg2, frel, fa1, fa2, nbf, hr, nhr, nrel, na1, na2, wh1, wh2, nf1,
        nf2, out, B, F);
    k_hop1<<<dim3(N / TN, B, 2), dim3(256), 0, stream>>>(ent, fa1, fa2, nf1, nf2, ne_,
                                                         wh1, nsc, B, N, F);
    k_topk<<<dim3(B, 2), dim3(256), N * sizeof(float), stream>>>(nsc, zval, zidx, B, N);
    k_hop2<<<dim3(KTOP, B, 2), dim3(256), 0, stream>>>(ent, fa1, fa2, nf1, nf2, ne_,
                                                       wh2, zval, zidx, out, B, N, F);
}

// Round 2
// 831.115 us; speedup vs baseline: 1.5473x; 1.5473x over previous
//
#include <hip/hip_runtime.h>
#include <math.h>

#define E 256
#define KTOP 10

typedef __attribute__((ext_vector_type(8))) short bf16x8;
typedef __attribute__((ext_vector_type(4))) float f32x4;

// ---------- helpers ----------
__device__ inline float wsum(float v) {
    v += __shfl_xor(v, 1, 64);
    v += __shfl_xor(v, 2, 64);
    v += __shfl_xor(v, 4, 64);
    v += __shfl_xor(v, 8, 64);
    v += __shfl_xor(v, 16, 64);
    v += __shfl_xor(v, 32, 64);
    return v;
}

__device__ inline float dot4(float4 a, float4 b) {
    return a.x * b.x + a.y * b.y + a.z * b.z + a.w * b.w;
}

__device__ inline float gk(float d) {  // Gaussian kernel on squared distance
    return expf(-0.5f * fmaxf(d, 0.0f));
}

__device__ inline void atomicMaxF(float* addr, float v) {
    // valid for non-negative floats only (uint order == float order)
    atomicMax((unsigned int*)addr, __float_as_uint(v));
}

__device__ inline unsigned short f2bf(float x) {  // RNE f32 -> bf16
    unsigned u = __float_as_uint(x);
    unsigned r = (u + 0x7FFFu + ((u >> 16) & 1u)) >> 16;
    return (unsigned short)r;
}

#define GLD16(g, l)                                                      \
    __builtin_amdgcn_global_load_lds(                                    \
        (const __attribute__((address_space(1))) void*)(g),              \
        (__attribute__((address_space(3))) void*)(l), 16, 0, 0)

// ---------- kernels ----------
__global__ void k_init(float* out, int B) {
    if ((int)threadIdx.x < B) out[threadIdx.x] = 0.0f;
}

__global__ void k_zero(float* p, int n) {
    int i = blockIdx.x * 256 + threadIdx.x;
    if (i < n) p[i] = 0.0f;
}

// hop_rel[rh][b][:] = rel[b] @ W[rh] + bias[rh];  nhr[rh][b] = ||hop_rel||^2
__global__ void k_hoprel(const float* __restrict__ rel, const float* __restrict__ W,
                         const float* __restrict__ bias, float* __restrict__ hr,
                         float* __restrict__ nhr, int B) {
    int b = blockIdx.x, rh = blockIdx.y;
    int j = threadIdx.x;  // 0..255
    __shared__ float relS[E];
    relS[j] = rel[b * E + j];
    __syncthreads();
    const float* Wp = W + (size_t)rh * E * E;
    float acc = bias[rh * E + j];
#pragma unroll 8
    for (int e = 0; e < E; ++e) acc = fmaf(relS[e], Wp[e * E + j], acc);
    hr[((size_t)rh * B + b) * E + j] = acc;
    float s = wsum(acc * acc);
    __shared__ float red[4];
    int wave = j >> 6;
    if ((j & 63) == 0) red[wave] = s;
    __syncthreads();
    if (j == 0) nhr[rh * B + b] = red[0] + red[1] + red[2] + red[3];
}

// squared norms of rows of length E (small inputs only)
__global__ void k_rownorm(const float* __restrict__ src, float* __restrict__ dst, int nrows) {
    int row = blockIdx.x * 4 + (threadIdx.x >> 6);
    if (row >= nrows) return;
    int lane = threadIdx.x & 63;
    float4 v = ((const float4*)(src + (size_t)row * E))[lane];
    float s = wsum(dot4(v, v));
    if (lane == 0) dst[row] = s;
}

// norms + bf16 conversion for the big tensors (fa1, fa2, ent) in one pass
__global__ void k_prep(const float* __restrict__ fa1, const float* __restrict__ fa2,
                       const float* __restrict__ ent, unsigned short* __restrict__ fa1b,
                       unsigned short* __restrict__ fa2b, unsigned short* __restrict__ entb,
                       float* __restrict__ nf1, float* __restrict__ nf2,
                       float* __restrict__ ne_, int BF, int BN) {
    int row = blockIdx.x * 4 + (threadIdx.x >> 6);
    int lane = threadIdx.x & 63;
    int total = 2 * BF + BN;
    if (row >= total) return;
    const float* src;
    unsigned short* dstb;
    float* dstn;
    int r;
    if (row < BF) { src = fa1; dstb = fa1b; dstn = nf1; r = row; }
    else if (row < 2 * BF) { src = fa2; dstb = fa2b; dstn = nf2; r = row - BF; }
    else { src = ent; dstb = entb; dstn = ne_; r = row - 2 * BF; }
    float4 v = ((const float4*)(src + (size_t)r * E))[lane];
    float s = wsum(dot4(v, v));
    if (lane == 0) dstn[r] = s;
    ushort4 o;
    o.x = f2bf(v.x); o.y = f2bf(v.y); o.z = f2bf(v.z); o.w = f2bf(v.w);
    ((ushort4*)(dstb + (size_t)r * E))[lane] = o;
}

// per-(b,f): all query-vs-fact kernels constant over entities (fp32 inputs).
__global__ void k_pairmap(const float* __restrict__ rel, const float* __restrict__ arg1,
                          const float* __restrict__ arg2, const float* __restrict__ frel,
                          const float* __restrict__ fa1, const float* __restrict__ fa2,
                          const int* __restrict__ nbf, const float* __restrict__ hr,
                          const float* __restrict__ nhr, const float* __restrict__ nrel,
                          const float* __restrict__ na1, const float* __restrict__ na2,
                          float* __restrict__ wh1, float* __restrict__ wh2,
                          const float* __restrict__ nf1, const float* __restrict__ nf2,
                          float* __restrict__ out, int B, int F) {
    int b = blockIdx.y;
    int f0 = blockIdx.x * 128;
    int tid = threadIdx.x;
    __shared__ float qS[7 * E];
    __shared__ float nq[7];
    for (int i = tid; i < 7 * E; i += 256) {
        int q = i >> 8, e = i & 255;
        float v;
        if (q == 0) v = rel[b * E + e];
        else if (q == 1) v = arg1[b * E + e];
        else if (q == 2) v = arg2[b * E + e];
        else v = hr[((size_t)(q - 3) * B + b) * E + e];
        qS[i] = v;
    }
    if (tid < 7)
        nq[tid] = (tid == 0) ? nrel[b] : (tid == 1) ? na1[b] : (tid == 2) ? na2[b]
                                                             : nhr[(tid - 3) * B + b];
    __syncthreads();
    int lane = tid & 63, wave = tid >> 6;
    const float4* q4 = (const float4*)qS;
    float4 qrel = q4[lane], qa1 = q4[64 + lane], qa2 = q4[128 + lane];
    float4 qh00 = q4[192 + lane], qh01 = q4[256 + lane], qh10 = q4[320 + lane],
           qh11 = q4[384 + lane];
    int nbfb = nbf[b];
    int fend = min(f0 + 128, F);
    for (int f = f0 + wave; f < fend; f += 4) {
        float4 v = ((const float4*)(frel + ((size_t)b * F + f) * E))[lane];
        float d_rel = dot4(v, qrel), d_h00 = dot4(v, qh00), d_h01 = dot4(v, qh01);
        float d_h10 = dot4(v, qh10), d_h11 = dot4(v, qh11), n_fr = dot4(v, v);
        float4 v1 = ((const float4*)(fa1 + ((size_t)b * F + f) * E))[lane];
        float d_a1f1 = dot4(v1, qa1), d_a2f1 = dot4(v1, qa2);
        float4 v2 = ((const float4*)(fa2 + ((size_t)b * F + f) * E))[lane];
        float d_a1f2 = dot4(v2, qa1), d_a2f2 = dot4(v2, qa2);
        d_rel = wsum(d_rel); d_h00 = wsum(d_h00); d_h01 = wsum(d_h01);
        d_h10 = wsum(d_h10); d_h11 = wsum(d_h11); n_fr = wsum(n_fr);
        d_a1f1 = wsum(d_a1f1); d_a2f1 = wsum(d_a2f1);
        d_a1f2 = wsum(d_a1f2); d_a2f2 = wsum(d_a2f2);
        if (lane == 0) {
            size_t bf = (size_t)b * F + f;
            float n_f1 = nf1[bf], n_f2 = nf2[bf];
            float m = (f < nbfb) ? 1.0f : 0.0f;
            float krel = gk(nq[0] + n_fr - 2.f * d_rel);
            float kh00 = gk(nq[3] + n_fr - 2.f * d_h00);
            float kh01 = gk(nq[4] + n_fr - 2.f * d_h01);
            float kh10 = gk(nq[5] + n_fr - 2.f * d_h10);
            float kh11 = gk(nq[6] + n_fr - 2.f * d_h11);
            float ka1f1 = gk(nq[1] + n_f1 - 2.f * d_a1f1);
            float ka2f1 = gk(nq[2] + n_f1 - 2.f * d_a2f1);
            float ka1f2 = gk(nq[1] + n_f2 - 2.f * d_a1f2);
            float ka2f2 = gk(nq[2] + n_f2 - 2.f * d_a2f2);
            wh1[bf] = kh00 * ka1f1 * m;                   // rule0 hop1 const part
            wh1[(size_t)B * F + bf] = kh10 * ka1f2 * m;   // rule1 hop1 const part
            wh2[bf] = kh01 * ka2f2 * m;                   // rule0 hop2 const part
            wh2[(size_t)B * F + bf] = kh11 * ka2f1 * m;   // rule1 hop2 const part
            atomicMaxF(&out[b], krel * ka1f1 * ka2f2 * m);  // scores_0
        }
    }
}

// hop1 via bf16 MFMA: nsc[r][b][n] = max_f wh1[r][b][f]*exp(-.5*relu(ne+nf-2*ent.fact))
// 128x128 tile, BK=32, 4 waves (each 64x64 = 4x4 fragments of 16x16x32).
// LDS layout: [koff 0..3][row 0..127][8 bf16] -> linear for global_load_lds,
// contiguous (conflict-free) for ds_read_b128.
__global__ __launch_bounds__(256) void k_hop1m(
    const unsigned short* __restrict__ entb, const unsigned short* __restrict__ fa1b,
    const unsigned short* __restrict__ fa2b, const float* __restrict__ nf1,
    const float* __restrict__ nf2, const float* __restrict__ ne,
    const float* __restrict__ wh1, float* __restrict__ nsc, int B, int N, int F) {
    int z = blockIdx.z;
    int r = z / B, b = z % B;
    int BR = blockIdx.x * 128;  // entity rows
    int CB = blockIdx.y * 128;  // fact cols
    const unsigned short* factb = (r == 0) ? fa2b : fa1b;
    const float* nfp = (r == 0) ? nf2 : nf1;
    const float* w = wh1 + ((size_t)r * B + b) * F;
    const float* nep = ne + (size_t)b * N;

    __shared__ unsigned short ldsA[512 * 8];  // 8 KB
    __shared__ unsigned short ldsB[512 * 8];  // 8 KB

    int tid = threadIdx.x, lane = tid & 63, wave = tid >> 6;
    int Rw = (wave >> 1) * 64, Cw = (wave & 1) * 64;
    int lr = lane & 15, lk = lane >> 4;

    const unsigned short* Ab = entb + ((size_t)b * N + BR) * E;
    const unsigned short* Bb = factb + ((size_t)b * F + CB) * E;

    f32x4 acc[4][4];
#pragma unroll
    for (int m = 0; m < 4; ++m)
#pragma unroll
        for (int n = 0; n < 4; ++n)
#pragma unroll
            for (int j = 0; j < 4; ++j) acc[m][n][j] = 0.0f;

    for (int kb = 0; kb < E / 32; ++kb) {
        int k0 = kb * 32;
#pragma unroll
        for (int is = 0; is < 2; ++is) {
            int sbase = is * 256 + wave * 64;  // wave-uniform slot base
            int sl = sbase + lane;
            int row = sl & 127, ko = sl >> 7;
            GLD16(Ab + (size_t)row * E + k0 + ko * 8, &ldsA[sbase * 8]);
            GLD16(Bb + (size_t)row * E + k0 + ko * 8, &ldsB[sbase * 8]);
        }
        __syncthreads();  // staging landed (vmcnt0 + barrier)
        bf16x8 af[4], bfr[4];
#pragma unroll
        for (int m = 0; m < 4; ++m)
            af[m] = *(const bf16x8*)&ldsA[((size_t)(lk * 128 + Rw + m * 16 + lr)) * 8];
#pragma unroll
        for (int n = 0; n < 4; ++n)
            bfr[n] = *(const bf16x8*)&ldsB[((size_t)(lk * 128 + Cw + n * 16 + lr)) * 8];
#pragma unroll
        for (int m = 0; m < 4; ++m)
#pragma unroll
            for (int n = 0; n < 4; ++n)
                acc[m][n] = __builtin_amdgcn_mfma_f32_16x16x32_bf16(af[m], bfr[n],
                                                                    acc[m][n], 0, 0, 0);
        __syncthreads();  // reads complete before next stage overwrites
    }

    // epilogue: kernel + masked-weight, max over this block's 128 f-cols
    float vmax[4][4];
#pragma unroll
    for (int m = 0; m < 4; ++m)
#pragma unroll
        for (int j = 0; j < 4; ++j) vmax[m][j] = 0.0f;
#pragma unroll
    for (int nfr = 0; nfr < 4; ++nfr) {
        int f = CB + Cw + nfr * 16 + lr;
        float wf = w[f];
        float nff = nfp[(size_t)b * F + f];
#pragma unroll
        for (int m = 0; m < 4; ++m) {
#pragma unroll
            for (int j = 0; j < 4; ++j) {
                int n = BR + Rw + m * 16 + lk * 4 + j;
                float d = nep[n] + nff - 2.0f * acc[m][nfr][j];
                float v = wf * expf(-0.5f * fmaxf(d, 0.0f));
                vmax[m][j] = fmaxf(vmax[m][j], v);
            }
        }
    }
    // reduce across the 16 lanes (lr) holding different f of the same rows
#pragma unroll
    for (int m = 0; m < 4; ++m)
#pragma unroll
        for (int j = 0; j < 4; ++j) {
            float v = vmax[m][j];
            v = fmaxf(v, __shfl_xor(v, 1, 64));
            v = fmaxf(v, __shfl_xor(v, 2, 64));
            v = fmaxf(v, __shfl_xor(v, 4, 64));
            v = fmaxf(v, __shfl_xor(v, 8, 64));
            if (lr == 0) {
                int n = BR + Rw + m * 16 + lk * 4 + j;
                atomicMaxF(&nsc[((size_t)r * B + b) * N + n], v);
            }
        }
}

// top-10 per (r,b) with jax.lax.top_k tie-breaking (lower index wins on equal value)
__global__ void k_topk(const float* __restrict__ nsc, float* __restrict__ zval,
                       int* __restrict__ zidx, int B, int N) {
    int b = blockIdx.x, r = blockIdx.y;
    int tid = threadIdx.x;
    extern __shared__ float sv[];  // N floats
    const float* src = nsc + ((size_t)r * B + b) * N;
    for (int i = tid; i < N; i += 256) sv[i] = src[i];
    __syncthreads();
    __shared__ float rv[256];
    __shared__ int ri[256];
    for (int t = 0; t < KTOP; ++t) {
        float bv = -1.f;
        int bi = 0;
        for (int i = tid; i < N; i += 256) {
            float v = sv[i];
            if (v > bv || (v == bv && i < bi)) { bv = v; bi = i; }
        }
        rv[tid] = bv; ri[tid] = bi;
        __syncthreads();
        for (int s = 128; s > 0; s >>= 1) {
            if (tid < s) {
                float v2 = rv[tid + s]; int i2 = ri[tid + s];
                if (v2 > rv[tid] || (v2 == rv[tid] && i2 < ri[tid])) {
                    rv[tid] = v2; ri[tid] = i2;
                }
            }
            __syncthreads();
        }
        if (tid == 0) {
            zval[((size_t)r * B + b) * KTOP + t] = rv[0];
            zidx[((size_t)r * B + b) * KTOP + t] = ri[0];
            sv[ri[0]] = -2.f;  // remove; all real values are >= 0
        }
        __syncthreads();
    }
}

// hop2 for the 10 selected sources per (r,b); fold min(hop2, hop1) max into out.
__global__ void k_hop2(const float* __restrict__ ent, const float* __restrict__ fa1,
                       const float* __restrict__ fa2, const float* __restrict__ nf1,
                       const float* __restrict__ nf2, const float* __restrict__ ne,
                       const float* __restrict__ wh2, const float* __restrict__ zval,
                       const int* __restrict__ zidx, float* __restrict__ out, int B,
                       int N, int F) {
    int k = blockIdx.x, b = blockIdx.y, r = blockIdx.z;
    const float* fact = (r == 0) ? fa1 : fa2;  // r0: src vs fact_arg1; r1: src vs fact_arg2
    const float* nf = (r == 0) ? nf1 : nf2;
    int tid = threadIdx.x, lane = tid & 63, wave = tid >> 6;
    int idx = zidx[((size_t)r * B + b) * KTOP + k];
    __shared__ float sS[E];
    sS[tid] = ent[((size_t)b * N + idx) * E + tid];
    __syncthreads();
    float nsrc = ne[(size_t)b * N + idx];
    float4 q = ((const float4*)sS)[lane];
    float vmax = 0.f;
    for (int f = wave; f < F; f += 4) {
        float4 v = *(const float4*)(fact + ((size_t)b * F + f) * E + lane * 4);
        float d = wsum(dot4(v, q));
        float wf = wh2[(size_t)r * B * F + (size_t)b * F + f];
        float val = wf * expf(-0.5f * fmaxf(nsrc + nf[(size_t)b * F + f] - 2.f * d, 0.f));
        vmax = fmaxf(vmax, val);
    }
    __shared__ float red[4];
    if (lane == 0) red[wave] = vmax;
    __syncthreads();
    if (tid == 0) {
        float z2 = fmaxf(fmaxf(red[0], red[1]), fmaxf(red[2], red[3]));
        float sc = fminf(z2, zval[((size_t)r * B + b) * KTOP + k]);
        atomicMaxF(&out[b], sc);
    }
}

// ---------- launcher ----------
extern "C" void kernel_launch(void* const* d_in, const int* in_sizes, int n_in,
                              void* d_out, int out_size, void* d_ws, size_t ws_size,
                              hipStream_t stream) {
    const float* rel = (const float*)d_in[0];
    const float* arg1 = (const float*)d_in[1];
    const float* arg2 = (const float*)d_in[2];
    const float* frel = (const float*)d_in[3];
    const float* fa1 = (const float*)d_in[4];
    const float* fa2 = (const float*)d_in[5];
    const int* nbf = (const int*)d_in[6];
    const float* ent = (const float*)d_in[7];
    const float* W = (const float*)d_in[9];
    const float* bias = (const float*)d_in[10];
    int B = in_sizes[0] / E;
    int F = in_sizes[3] / (B * E);
    int N = in_sizes[7] / (B * E);
    float* out = (float*)d_out;

    float* ws = (float*)d_ws;
    size_t o = 0;
    float* hr = ws + o;   o += (size_t)4 * B * E;
    float* nhr = ws + o;  o += (size_t)4 * B;
    float* nrel = ws + o; o += B;
    float* na1 = ws + o;  o += B;
    float* na2 = ws + o;  o += B;
    float* nf1 = ws + o;  o += (size_t)B * F;
    float* nf2 = ws + o;  o += (size_t)B * F;
    float* ne_ = ws + o;  o += (size_t)B * N;
    float* wh1 = ws + o;  o += (size_t)2 * B * F;
    float* wh2 = ws + o;  o += (size_t)2 * B * F;
    float* nsc = ws + o;  o += (size_t)2 * B * N;
    float* zval = ws + o; o += (size_t)2 * B * KTOP;
    int* zidx = (int*)(ws + o); o += (size_t)2 * B * KTOP;
    unsigned short* fa1b = (unsigned short*)(ws + o); o += (size_t)B * F * E / 2;
    unsigned short* fa2b = (unsigned short*)(ws + o); o += (size_t)B * F * E / 2;
    unsigned short* entb = (unsigned short*)(ws + o); o += (size_t)B * N * E / 2;

    k_init<<<dim3(1), dim3(64), 0, stream>>>(out, B);
    k_zero<<<dim3((2 * B * N + 255) / 256), dim3(256), 0, stream>>>(nsc, 2 * B * N);
    k_hoprel<<<dim3(B, 4), dim3(E), 0, stream>>>(rel, W, bias, hr, nhr, B);
    k_rownorm<<<dim3((B + 3) / 4), dim3(256), 0, stream>>>(rel, nrel, B);
    k_rownorm<<<dim3((B + 3) / 4), dim3(256), 0, stream>>>(arg1, na1, B);
    k_rownorm<<<dim3((B + 3) / 4), dim3(256), 0, stream>>>(arg2, na2, B);
    int totrows = 2 * B * F + B * N;
    k_prep<<<dim3((totrows + 3) / 4), dim3(256), 0, stream>>>(
        fa1, fa2, ent, fa1b, fa2b, entb, nf1, nf2, ne_, B * F, B * N);
    k_pairmap<<<dim3((F + 127) / 128, B), dim3(256), 0, stream>>>(
        rel, arg1, arg2, frel, fa1, fa2, nbf, hr, nhr, nrel, na1, na2, wh1, wh2, nf1,
        nf2, out, B, F);
    k_hop1m<<<dim3(N / 128, F / 128, 2 * B), dim3(256), 0, stream>>>(
        entb, fa1b, fa2b, nf1, nf2, ne_, wh1, nsc, B, N, F);
    k_topk<<<dim3(B, 2), dim3(256), N * sizeof(float), stream>>>(nsc, zval, zidx, B, N);
    k_hop2<<<dim3(KTOP, B, 2), dim3(256), 0, stream>>>(ent, fa1, fa2, nf1, nf2, ne_,
                                                       wh2, zval, zidx, out, B, N, F);
}

// Round 3
// 301.909 us; speedup vs baseline: 4.2594x; 2.7529x over previous
//
#include <hip/hip_runtime.h>
#include <math.h>

#define E 256
#define KTOP 10
#define H2CH 8

typedef __attribute__((ext_vector_type(8))) short bf16x8;
typedef __attribute__((ext_vector_type(4))) float f32x4;

// ---------- helpers ----------
__device__ inline float wsum(float v) {
    v += __shfl_xor(v, 1, 64);
    v += __shfl_xor(v, 2, 64);
    v += __shfl_xor(v, 4, 64);
    v += __shfl_xor(v, 8, 64);
    v += __shfl_xor(v, 16, 64);
    v += __shfl_xor(v, 32, 64);
    return v;
}

__device__ inline float wmax(float v) {
    v = fmaxf(v, __shfl_xor(v, 1, 64));
    v = fmaxf(v, __shfl_xor(v, 2, 64));
    v = fmaxf(v, __shfl_xor(v, 4, 64));
    v = fmaxf(v, __shfl_xor(v, 8, 64));
    v = fmaxf(v, __shfl_xor(v, 16, 64));
    v = fmaxf(v, __shfl_xor(v, 32, 64));
    return v;
}

__device__ inline float dot4(float4 a, float4 b) {
    return a.x * b.x + a.y * b.y + a.z * b.z + a.w * b.w;
}

__device__ inline float gk(float d) {  // Gaussian kernel on squared distance
    return expf(-0.5f * fmaxf(d, 0.0f));
}

__device__ inline void atomicMaxF(float* addr, float v) {
    // valid for non-negative floats only (uint order == float order)
    atomicMax((unsigned int*)addr, __float_as_uint(v));
}

__device__ inline unsigned short f2bf(float x) {  // RNE f32 -> bf16
    unsigned u = __float_as_uint(x);
    unsigned r = (u + 0x7FFFu + ((u >> 16) & 1u)) >> 16;
    return (unsigned short)r;
}

#define GLD16(g, l)                                                      \
    __builtin_amdgcn_global_load_lds(                                    \
        (const __attribute__((address_space(1))) void*)(g),              \
        (__attribute__((address_space(3))) void*)(l), 16, 0, 0)

// ---------- kernels ----------
__global__ void k_zero(float* p, int n) {
    int i = blockIdx.x * 256 + threadIdx.x;
    if (i < n) p[i] = 0.0f;
}

// hop_rel[rh][b][:] = rel[b] @ W[rh] + bias[rh];  nhr[rh][b] = ||hop_rel||^2
__global__ void k_hoprel(const float* __restrict__ rel, const float* __restrict__ W,
                         const float* __restrict__ bias, float* __restrict__ hr,
                         float* __restrict__ nhr, int B) {
    int b = blockIdx.x, rh = blockIdx.y;
    int j = threadIdx.x;  // 0..255
    __shared__ float relS[E];
    relS[j] = rel[b * E + j];
    __syncthreads();
    const float* Wp = W + (size_t)rh * E * E;
    float acc = bias[rh * E + j];
#pragma unroll 8
    for (int e = 0; e < E; ++e) acc = fmaf(relS[e], Wp[e * E + j], acc);
    hr[((size_t)rh * B + b) * E + j] = acc;
    float s = wsum(acc * acc);
    __shared__ float red[4];
    int wave = j >> 6;
    if ((j & 63) == 0) red[wave] = s;
    __syncthreads();
    if (j == 0) nhr[rh * B + b] = red[0] + red[1] + red[2] + red[3];
}

// squared norms of rows of length E (small inputs only)
__global__ void k_rownorm(const float* __restrict__ src, float* __restrict__ dst, int nrows) {
    int row = blockIdx.x * 4 + (threadIdx.x >> 6);
    if (row >= nrows) return;
    int lane = threadIdx.x & 63;
    float4 v = ((const float4*)(src + (size_t)row * E))[lane];
    float s = wsum(dot4(v, v));
    if (lane == 0) dst[row] = s;
}

// norms + bf16 conversion for the big tensors (fa1, fa2, ent) in one pass
__global__ void k_prep(const float* __restrict__ fa1, const float* __restrict__ fa2,
                       const float* __restrict__ ent, unsigned short* __restrict__ fa1b,
                       unsigned short* __restrict__ fa2b, unsigned short* __restrict__ entb,
                       float* __restrict__ nf1, float* __restrict__ nf2,
                       float* __restrict__ ne_, int BF, int BN) {
    int row = blockIdx.x * 4 + (threadIdx.x >> 6);
    int lane = threadIdx.x & 63;
    int total = 2 * BF + BN;
    if (row >= total) return;
    const float* src;
    unsigned short* dstb;
    float* dstn;
    int r;
    if (row < BF) { src = fa1; dstb = fa1b; dstn = nf1; r = row; }
    else if (row < 2 * BF) { src = fa2; dstb = fa2b; dstn = nf2; r = row - BF; }
    else { src = ent; dstb = entb; dstn = ne_; r = row - 2 * BF; }
    float4 v = ((const float4*)(src + (size_t)r * E))[lane];
    float s = wsum(dot4(v, v));
    if (lane == 0) dstn[r] = s;
    ushort4 o;
    o.x = f2bf(v.x); o.y = f2bf(v.y); o.z = f2bf(v.z); o.w = f2bf(v.w);
    ((ushort4*)(dstb + (size_t)r * E))[lane] = o;
}

// wave-per-fact: all query-vs-fact kernels constant over entities.
__global__ __launch_bounds__(256) void k_pairmap(
    const float* __restrict__ rel, const float* __restrict__ arg1,
    const float* __restrict__ arg2, const float* __restrict__ frel,
    const float* __restrict__ fa1, const float* __restrict__ fa2,
    const int* __restrict__ nbf, const float* __restrict__ hr,
    const float* __restrict__ nhr, const float* __restrict__ nrel,
    const float* __restrict__ na1, const float* __restrict__ na2,
    float* __restrict__ wh1, float* __restrict__ wh2,
    const float* __restrict__ nf1, const float* __restrict__ nf2,
    float* __restrict__ s0buf, int B, int F) {
    int b = blockIdx.y;
    int lane = threadIdx.x & 63, wave = threadIdx.x >> 6;
    int f = blockIdx.x * 4 + wave;
    size_t bf = (size_t)b * F + f;
    // query slices (L1/L2-resident after first block touching this b)
    float4 qrel = ((const float4*)(rel + (size_t)b * E))[lane];
    float4 qa1  = ((const float4*)(arg1 + (size_t)b * E))[lane];
    float4 qa2  = ((const float4*)(arg2 + (size_t)b * E))[lane];
    float4 qh00 = ((const float4*)(hr + ((size_t)0 * B + b) * E))[lane];
    float4 qh01 = ((const float4*)(hr + ((size_t)1 * B + b) * E))[lane];
    float4 qh10 = ((const float4*)(hr + ((size_t)2 * B + b) * E))[lane];
    float4 qh11 = ((const float4*)(hr + ((size_t)3 * B + b) * E))[lane];
    // fact rows (fresh)
    float4 v  = ((const float4*)(frel + bf * E))[lane];
    float4 v1 = ((const float4*)(fa1 + bf * E))[lane];
    float4 v2 = ((const float4*)(fa2 + bf * E))[lane];
    // 10 independent reductions (ILP across chains)
    float d_rel  = wsum(dot4(v, qrel));
    float d_h00  = wsum(dot4(v, qh00));
    float d_h01  = wsum(dot4(v, qh01));
    float d_h10  = wsum(dot4(v, qh10));
    float d_h11  = wsum(dot4(v, qh11));
    float n_fr   = wsum(dot4(v, v));
    float d_a1f1 = wsum(dot4(v1, qa1));
    float d_a2f1 = wsum(dot4(v1, qa2));
    float d_a1f2 = wsum(dot4(v2, qa1));
    float d_a2f2 = wsum(dot4(v2, qa2));
    if (lane == 0) {
        float n_f1 = nf1[bf], n_f2 = nf2[bf];
        float m = (f < nbf[b]) ? 1.0f : 0.0f;
        float krel  = gk(nrel[b] + n_fr - 2.f * d_rel);
        float kh00  = gk(nhr[0 * B + b] + n_fr - 2.f * d_h00);
        float kh01  = gk(nhr[1 * B + b] + n_fr - 2.f * d_h01);
        float kh10  = gk(nhr[2 * B + b] + n_fr - 2.f * d_h10);
        float kh11  = gk(nhr[3 * B + b] + n_fr - 2.f * d_h11);
        float ka1f1 = gk(na1[b] + n_f1 - 2.f * d_a1f1);
        float ka2f1 = gk(na2[b] + n_f1 - 2.f * d_a2f1);
        float ka1f2 = gk(na1[b] + n_f2 - 2.f * d_a1f2);
        float ka2f2 = gk(na2[b] + n_f2 - 2.f * d_a2f2);
        wh1[bf] = kh00 * ka1f1 * m;                   // rule0 hop1 const part
        wh1[(size_t)B * F + bf] = kh10 * ka1f2 * m;   // rule1 hop1 const part
        wh2[bf] = kh01 * ka2f2 * m;                   // rule0 hop2 const part
        wh2[(size_t)B * F + bf] = kh11 * ka2f1 * m;   // rule1 hop2 const part
        s0buf[bf] = krel * ka1f1 * ka2f2 * m;         // scores_0 contribution
    }
}

// out[b] = max_f s0buf[b][f]  (replaces init of out; no atomics)
__global__ void k_s0red(const float* __restrict__ s0buf, float* __restrict__ out,
                        int B, int F) {
    int b = blockIdx.x;
    int tid = threadIdx.x, lane = tid & 63, wave = tid >> 6;
    float m = 0.f;
    for (int f = tid; f < F; f += 256) m = fmaxf(m, s0buf[(size_t)b * F + f]);
    m = wmax(m);
    __shared__ float red[4];
    if (lane == 0) red[wave] = m;
    __syncthreads();
    if (tid == 0) out[b] = fmaxf(fmaxf(red[0], red[1]), fmaxf(red[2], red[3]));
}

// hop1 via bf16 MFMA: nsc[r][b][n] = max_f wh1[r][b][f]*exp(-.5*relu(ne+nf-2*ent.fact))
// 128x128 tile, BK=32, 4 waves (each 64x64 = 4x4 fragments of 16x16x32).
__global__ __launch_bounds__(256) void k_hop1m(
    const unsigned short* __restrict__ entb, const unsigned short* __restrict__ fa1b,
    const unsigned short* __restrict__ fa2b, const float* __restrict__ nf1,
    const float* __restrict__ nf2, const float* __restrict__ ne,
    const float* __restrict__ wh1, float* __restrict__ nsc, int B, int N, int F) {
    int z = blockIdx.z;
    int r = z / B, b = z % B;
    int BR = blockIdx.x * 128;  // entity rows
    int CB = blockIdx.y * 128;  // fact cols
    const unsigned short* factb = (r == 0) ? fa2b : fa1b;
    const float* nfp = (r == 0) ? nf2 : nf1;
    const float* w = wh1 + ((size_t)r * B + b) * F;
    const float* nep = ne + (size_t)b * N;

    __shared__ unsigned short ldsA[512 * 8];  // 8 KB
    __shared__ unsigned short ldsB[512 * 8];  // 8 KB

    int tid = threadIdx.x, lane = tid & 63, wave = tid >> 6;
    int Rw = (wave >> 1) * 64, Cw = (wave & 1) * 64;
    int lr = lane & 15, lk = lane >> 4;

    const unsigned short* Ab = entb + ((size_t)b * N + BR) * E;
    const unsigned short* Bb = factb + ((size_t)b * F + CB) * E;

    f32x4 acc[4][4];
#pragma unroll
    for (int m = 0; m < 4; ++m)
#pragma unroll
        for (int n = 0; n < 4; ++n)
#pragma unroll
            for (int j = 0; j < 4; ++j) acc[m][n][j] = 0.0f;

    for (int kb = 0; kb < E / 32; ++kb) {
        int k0 = kb * 32;
#pragma unroll
        for (int is = 0; is < 2; ++is) {
            int sbase = is * 256 + wave * 64;  // wave-uniform slot base
            int sl = sbase + lane;
            int row = sl & 127, ko = sl >> 7;
            GLD16(Ab + (size_t)row * E + k0 + ko * 8, &ldsA[sbase * 8]);
            GLD16(Bb + (size_t)row * E + k0 + ko * 8, &ldsB[sbase * 8]);
        }
        __syncthreads();  // staging landed (vmcnt0 + barrier)
        bf16x8 af[4], bfr[4];
#pragma unroll
        for (int m = 0; m < 4; ++m)
            af[m] = *(const bf16x8*)&ldsA[((size_t)(lk * 128 + Rw + m * 16 + lr)) * 8];
#pragma unroll
        for (int n = 0; n < 4; ++n)
            bfr[n] = *(const bf16x8*)&ldsB[((size_t)(lk * 128 + Cw + n * 16 + lr)) * 8];
#pragma unroll
        for (int m = 0; m < 4; ++m)
#pragma unroll
            for (int n = 0; n < 4; ++n)
                acc[m][n] = __builtin_amdgcn_mfma_f32_16x16x32_bf16(af[m], bfr[n],
                                                                    acc[m][n], 0, 0, 0);
        __syncthreads();  // reads complete before next stage overwrites
    }

    // epilogue: kernel + masked-weight, max over this block's 128 f-cols
    float vmax[4][4];
#pragma unroll
    for (int m = 0; m < 4; ++m)
#pragma unroll
        for (int j = 0; j < 4; ++j) vmax[m][j] = 0.0f;
#pragma unroll
    for (int nfr = 0; nfr < 4; ++nfr) {
        int f = CB + Cw + nfr * 16 + lr;
        float wf = w[f];
        float nff = nfp[(size_t)b * F + f];
#pragma unroll
        for (int m = 0; m < 4; ++m) {
#pragma unroll
            for (int j = 0; j < 4; ++j) {
                int n = BR + Rw + m * 16 + lk * 4 + j;
                float d = nep[n] + nff - 2.0f * acc[m][nfr][j];
                float v = wf * expf(-0.5f * fmaxf(d, 0.0f));
                vmax[m][j] = fmaxf(vmax[m][j], v);
            }
        }
    }
#pragma unroll
    for (int m = 0; m < 4; ++m)
#pragma unroll
        for (int j = 0; j < 4; ++j) {
            float v = vmax[m][j];
            v = fmaxf(v, __shfl_xor(v, 1, 64));
            v = fmaxf(v, __shfl_xor(v, 2, 64));
            v = fmaxf(v, __shfl_xor(v, 4, 64));
            v = fmaxf(v, __shfl_xor(v, 8, 64));
            if (lr == 0) {
                int n = BR + Rw + m * 16 + lk * 4 + j;
                atomicMaxF(&nsc[((size_t)r * B + b) * N + n], v);
            }
        }
}

// top-10 per (r,b) with jax.lax.top_k tie-breaking (lower index wins on equal value)
__global__ void k_topk(const float* __restrict__ nsc, float* __restrict__ zval,
                       int* __restrict__ zidx, int B, int N) {
    int b = blockIdx.x, r = blockIdx.y;
    int tid = threadIdx.x;
    extern __shared__ float sv[];  // N floats
    const float* src = nsc + ((size_t)r * B + b) * N;
    for (int i = tid; i < N; i += 256) sv[i] = src[i];
    __syncthreads();
    __shared__ float rv[256];
    __shared__ int ri[256];
    for (int t = 0; t < KTOP; ++t) {
        float bv = -1.f;
        int bi = 0;
        for (int i = tid; i < N; i += 256) {
            float v = sv[i];
            if (v > bv || (v == bv && i < bi)) { bv = v; bi = i; }
        }
        rv[tid] = bv; ri[tid] = bi;
        __syncthreads();
        for (int s = 128; s > 0; s >>= 1) {
            if (tid < s) {
                float v2 = rv[tid + s]; int i2 = ri[tid + s];
                if (v2 > rv[tid] || (v2 == rv[tid] && i2 < ri[tid])) {
                    rv[tid] = v2; ri[tid] = i2;
                }
            }
            __syncthreads();
        }
        if (tid == 0) {
            zval[((size_t)r * B + b) * KTOP + t] = rv[0];
            zidx[((size_t)r * B + b) * KTOP + t] = ri[0];
            sv[ri[0]] = -2.f;  // remove; all real values are >= 0
        }
        __syncthreads();
    }
}

// hop2 partial: f-chunked max for the 10 selected sources per (r,b)
__global__ __launch_bounds__(256) void k_hop2p(
    const float* __restrict__ ent, const float* __restrict__ fa1,
    const float* __restrict__ fa2, const float* __restrict__ nf1,
    const float* __restrict__ nf2, const float* __restrict__ ne,
    const float* __restrict__ wh2, const int* __restrict__ zidx,
    float* __restrict__ h2max, int B, int N, int F) {
    int k = blockIdx.x, b = blockIdx.y;
    int rc = blockIdx.z;
    int r = rc >> 3, c = rc & (H2CH - 1);
    const float* fact = (r == 0) ? fa1 : fa2;  // r0: src vs fact_arg1; r1: src vs fact_arg2
    const float* nf = (r == 0) ? nf1 : nf2;
    int tid = threadIdx.x, lane = tid & 63, wave = tid >> 6;
    int idx = zidx[((size_t)r * B + b) * KTOP + k];
    float4 q = ((const float4*)(ent + ((size_t)b * N + idx) * E))[lane];
    float nsrc = ne[(size_t)b * N + idx];
    int fchunk = F / H2CH;
    int fbeg = c * fchunk, fend = fbeg + fchunk;
    float vmax = 0.f;
    for (int f = fbeg + wave; f < fend; f += 4) {
        float4 v = ((const float4*)(fact + ((size_t)b * F + f) * E))[lane];
        float d = wsum(dot4(v, q));
        float wf = wh2[(size_t)r * B * F + (size_t)b * F + f];
        float val = wf * expf(-0.5f * fmaxf(nsrc + nf[(size_t)b * F + f] - 2.f * d, 0.f));
        vmax = fmaxf(vmax, val);
    }
    __shared__ float red[4];
    if (lane == 0) red[wave] = vmax;
    __syncthreads();
    if (tid == 0) {
        float z2 = fmaxf(fmaxf(red[0], red[1]), fmaxf(red[2], red[3]));
        atomicMaxF(&h2max[((size_t)r * B + b) * KTOP + k], z2);
    }
}

// combine: out[b] = max(out[b], min(h2max, zval)) over all (r,k)
__global__ void k_hop2c(const float* __restrict__ h2max, const float* __restrict__ zval,
                        float* __restrict__ out, int B) {
    int i = blockIdx.x * 256 + threadIdx.x;
    int n = 2 * B * KTOP;
    if (i < n) {
        int b = (i / KTOP) % B;
        float sc = fminf(h2max[i], zval[i]);
        atomicMaxF(&out[b], sc);
    }
}

// ---------- launcher ----------
extern "C" void kernel_launch(void* const* d_in, const int* in_sizes, int n_in,
                              void* d_out, int out_size, void* d_ws, size_t ws_size,
                              hipStream_t stream) {
    const float* rel = (const float*)d_in[0];
    const float* arg1 = (const float*)d_in[1];
    const float* arg2 = (const float*)d_in[2];
    const float* frel = (const float*)d_in[3];
    const float* fa1 = (const float*)d_in[4];
    const float* fa2 = (const float*)d_in[5];
    const int* nbf = (const int*)d_in[6];
    const float* ent = (const float*)d_in[7];
    const float* W = (const float*)d_in[9];
    const float* bias = (const float*)d_in[10];
    int B = in_sizes[0] / E;
    int F = in_sizes[3] / (B * E);
    int N = in_sizes[7] / (B * E);
    float* out = (float*)d_out;

    float* ws = (float*)d_ws;
    size_t o = 0;
    float* hr = ws + o;   o += (size_t)4 * B * E;
    float* nhr = ws + o;  o += (size_t)4 * B;
    float* nrel = ws + o; o += B;
    float* na1 = ws + o;  o += B;
    float* na2 = ws + o;  o += B;
    float* nf1 = ws + o;  o += (size_t)B * F;
    float* nf2 = ws + o;  o += (size_t)B * F;
    float* ne_ = ws + o;  o += (size_t)B * N;
    float* wh1 = ws + o;  o += (size_t)2 * B * F;
    float* wh2 = ws + o;  o += (size_t)2 * B * F;
    float* nsc = ws + o;  o += (size_t)2 * B * N;
    float* zval = ws + o; o += (size_t)2 * B * KTOP;
    int* zidx = (int*)(ws + o); o += (size_t)2 * B * KTOP;
    float* s0buf = ws + o; o += (size_t)B * F;
    float* h2max = ws + o; o += (size_t)2 * B * KTOP;
    unsigned short* fa1b = (unsigned short*)(ws + o); o += (size_t)B * F * E / 2;
    unsigned short* fa2b = (unsigned short*)(ws + o); o += (size_t)B * F * E / 2;
    unsigned short* entb = (unsigned short*)(ws + o); o += (size_t)B * N * E / 2;

    k_zero<<<dim3((2 * B * N + 255) / 256), dim3(256), 0, stream>>>(nsc, 2 * B * N);
    k_zero<<<dim3((2 * B * KTOP + 255) / 256), dim3(256), 0, stream>>>(h2max,
                                                                       2 * B * KTOP);
    k_hoprel<<<dim3(B, 4), dim3(E), 0, stream>>>(rel, W, bias, hr, nhr, B);
    k_rownorm<<<dim3((B + 3) / 4), dim3(256), 0, stream>>>(rel, nrel, B);
    k_rownorm<<<dim3((B + 3) / 4), dim3(256), 0, stream>>>(arg1, na1, B);
    k_rownorm<<<dim3((B + 3) / 4), dim3(256), 0, stream>>>(arg2, na2, B);
    int totrows = 2 * B * F + B * N;
    k_prep<<<dim3((totrows + 3) / 4), dim3(256), 0, stream>>>(
        fa1, fa2, ent, fa1b, fa2b, entb, nf1, nf2, ne_, B * F, B * N);
    k_pairmap<<<dim3(F / 4, B), dim3(256), 0, stream>>>(
        rel, arg1, arg2, frel, fa1, fa2, nbf, hr, nhr, nrel, na1, na2, wh1, wh2, nf1,
        nf2, s0buf, B, F);
    k_s0red<<<dim3(B), dim3(256), 0, stream>>>(s0buf, out, B, F);
    k_hop1m<<<dim3(N / 128, F / 128, 2 * B), dim3(256), 0, stream>>>(
        entb, fa1b, fa2b, nf1, nf2, ne_, wh1, nsc, B, N, F);
    k_topk<<<dim3(B, 2), dim3(256), N * sizeof(float), stream>>>(nsc, zval, zidx, B, N);
    k_hop2p<<<dim3(KTOP, B, 2 * H2CH), dim3(256), 0, stream>>>(
        ent, fa1, fa2, nf1, nf2, ne_, wh2, zidx, h2max, B, N, F);
    k_hop2c<<<dim3((2 * B * KTOP + 255) / 256), dim3(256), 0, stream>>>(h2max, zval,
                                                                        out, B);
}

// Round 4
// 291.384 us; speedup vs baseline: 4.4133x; 1.0361x over previous
//
#include <hip/hip_runtime.h>
#include <math.h>

#define E 256
#define KTOP 10
#define H2CH 8
#define NINF (-__builtin_huge_valf())

typedef __attribute__((ext_vector_type(8))) short bf16x8;
typedef __attribute__((ext_vector_type(4))) float f32x4;

// ---------- helpers ----------
__device__ inline float wsum(float v) {
    v += __shfl_xor(v, 1, 64);
    v += __shfl_xor(v, 2, 64);
    v += __shfl_xor(v, 4, 64);
    v += __shfl_xor(v, 8, 64);
    v += __shfl_xor(v, 16, 64);
    v += __shfl_xor(v, 32, 64);
    return v;
}

__device__ inline float wmax(float v) {
    v = fmaxf(v, __shfl_xor(v, 1, 64));
    v = fmaxf(v, __shfl_xor(v, 2, 64));
    v = fmaxf(v, __shfl_xor(v, 4, 64));
    v = fmaxf(v, __shfl_xor(v, 8, 64));
    v = fmaxf(v, __shfl_xor(v, 16, 64));
    v = fmaxf(v, __shfl_xor(v, 32, 64));
    return v;
}

__device__ inline float dot4(float4 a, float4 b) {
    return a.x * b.x + a.y * b.y + a.z * b.z + a.w * b.w;
}

__device__ inline void atomicMaxF(float* addr, float v) {
    // valid for non-negative floats only (uint order == float order)
    atomicMax((unsigned int*)addr, __float_as_uint(v));
}

__device__ inline unsigned short f2bf(float x) {  // RNE f32 -> bf16
    unsigned u = __float_as_uint(x);
    unsigned r = (u + 0x7FFFu + ((u >> 16) & 1u)) >> 16;
    return (unsigned short)r;
}

#define GLD16(g, l)                                                      \
    __builtin_amdgcn_global_load_lds(                                    \
        (const __attribute__((address_space(1))) void*)(g),              \
        (__attribute__((address_space(3))) void*)(l), 16, 0, 0)

// ---------- kernels ----------
// hop_rel[rh][b][:] = rel[b] @ W[rh] + bias[rh];  nhr[rh][b] = ||hop_rel||^2
__global__ void k_hoprel(const float* __restrict__ rel, const float* __restrict__ W,
                         const float* __restrict__ bias, float* __restrict__ hr,
                         float* __restrict__ nhr, int B) {
    int b = blockIdx.x, rh = blockIdx.y;
    int j = threadIdx.x;  // 0..255
    __shared__ float relS[E];
    relS[j] = rel[b * E + j];
    __syncthreads();
    const float* Wp = W + (size_t)rh * E * E;
    float acc = bias[rh * E + j];
#pragma unroll 8
    for (int e = 0; e < E; ++e) acc = fmaf(relS[e], Wp[e * E + j], acc);
    hr[((size_t)rh * B + b) * E + j] = acc;
    float s = wsum(acc * acc);
    __shared__ float red[4];
    int wave = j >> 6;
    if ((j & 63) == 0) red[wave] = s;
    __syncthreads();
    if (j == 0) nhr[rh * B + b] = red[0] + red[1] + red[2] + red[3];
}

// squared norms of rows of length E (small inputs only)
__global__ void k_rownorm(const float* __restrict__ src, float* __restrict__ dst, int nrows) {
    int row = blockIdx.x * 4 + (threadIdx.x >> 6);
    if (row >= nrows) return;
    int lane = threadIdx.x & 63;
    float4 v = ((const float4*)(src + (size_t)row * E))[lane];
    float s = wsum(dot4(v, v));
    if (lane == 0) dst[row] = s;
}

// norms + bf16 conversion for the big tensors (fa1, fa2, ent) in one pass
__global__ void k_prep(const float* __restrict__ fa1, const float* __restrict__ fa2,
                       const float* __restrict__ ent, unsigned short* __restrict__ fa1b,
                       unsigned short* __restrict__ fa2b, unsigned short* __restrict__ entb,
                       float* __restrict__ nf1, float* __restrict__ nf2,
                       float* __restrict__ ne_, int BF, int BN) {
    int row = blockIdx.x * 4 + (threadIdx.x >> 6);
    int lane = threadIdx.x & 63;
    int total = 2 * BF + BN;
    if (row >= total) return;
    const float* src;
    unsigned short* dstb;
    float* dstn;
    int r;
    if (row < BF) { src = fa1; dstb = fa1b; dstn = nf1; r = row; }
    else if (row < 2 * BF) { src = fa2; dstb = fa2b; dstn = nf2; r = row - BF; }
    else { src = ent; dstb = entb; dstn = ne_; r = row - 2 * BF; }
    float4 v = ((const float4*)(src + (size_t)r * E))[lane];
    float s = wsum(dot4(v, v));
    if (lane == 0) dstn[r] = s;
    ushort4 o;
    o.x = f2bf(v.x); o.y = f2bf(v.y); o.z = f2bf(v.z); o.w = f2bf(v.w);
    ((ushort4*)(dstb + (size_t)r * E))[lane] = o;
}

// wave-per-fact: log-space weights constant over entities. No transcendentals.
__global__ __launch_bounds__(256) void k_pairmap(
    const float* __restrict__ rel, const float* __restrict__ arg1,
    const float* __restrict__ arg2, const float* __restrict__ frel,
    const float* __restrict__ fa1, const float* __restrict__ fa2,
    const int* __restrict__ nbf, const float* __restrict__ hr,
    const float* __restrict__ nhr, const float* __restrict__ nrel,
    const float* __restrict__ na1, const float* __restrict__ na2,
    float* __restrict__ lw1, float* __restrict__ lw2,
    const float* __restrict__ nf1, const float* __restrict__ nf2,
    float* __restrict__ s0log, int B, int F) {
    int b = blockIdx.y;
    int lane = threadIdx.x & 63, wave = threadIdx.x >> 6;
    int f = blockIdx.x * 4 + wave;
    size_t bf = (size_t)b * F + f;
    float4 qrel = ((const float4*)(rel + (size_t)b * E))[lane];
    float4 qa1  = ((const float4*)(arg1 + (size_t)b * E))[lane];
    float4 qa2  = ((const float4*)(arg2 + (size_t)b * E))[lane];
    float4 qh00 = ((const float4*)(hr + ((size_t)0 * B + b) * E))[lane];
    float4 qh01 = ((const float4*)(hr + ((size_t)1 * B + b) * E))[lane];
    float4 qh10 = ((const float4*)(hr + ((size_t)2 * B + b) * E))[lane];
    float4 qh11 = ((const float4*)(hr + ((size_t)3 * B + b) * E))[lane];
    float4 v  = ((const float4*)(frel + bf * E))[lane];
    float4 v1 = ((const float4*)(fa1 + bf * E))[lane];
    float4 v2 = ((const float4*)(fa2 + bf * E))[lane];
    float d_rel  = wsum(dot4(v, qrel));
    float d_h00  = wsum(dot4(v, qh00));
    float d_h01  = wsum(dot4(v, qh01));
    float d_h10  = wsum(dot4(v, qh10));
    float d_h11  = wsum(dot4(v, qh11));
    float n_fr   = wsum(dot4(v, v));
    float d_a1f1 = wsum(dot4(v1, qa1));
    float d_a2f1 = wsum(dot4(v1, qa2));
    float d_a1f2 = wsum(dot4(v2, qa1));
    float d_a2f2 = wsum(dot4(v2, qa2));
    if (lane == 0) {
        float n_f1 = nf1[bf], n_f2 = nf2[bf];
        bool msk = (f < nbf[b]);
        // relu'd squared distances
        float rrel  = fmaxf(nrel[b] + n_fr - 2.f * d_rel, 0.f);
        float rh00  = fmaxf(nhr[0 * B + b] + n_fr - 2.f * d_h00, 0.f);
        float rh01  = fmaxf(nhr[1 * B + b] + n_fr - 2.f * d_h01, 0.f);
        float rh10  = fmaxf(nhr[2 * B + b] + n_fr - 2.f * d_h10, 0.f);
        float rh11  = fmaxf(nhr[3 * B + b] + n_fr - 2.f * d_h11, 0.f);
        float ra1f1 = fmaxf(na1[b] + n_f1 - 2.f * d_a1f1, 0.f);
        float ra2f1 = fmaxf(na2[b] + n_f1 - 2.f * d_a2f1, 0.f);
        float ra1f2 = fmaxf(na1[b] + n_f2 - 2.f * d_a1f2, 0.f);
        float ra2f2 = fmaxf(na2[b] + n_f2 - 2.f * d_a2f2, 0.f);
        lw1[bf]                 = msk ? -0.5f * (rh00 + ra1f1) : NINF;  // rule0 hop1
        lw1[(size_t)B * F + bf] = msk ? -0.5f * (rh10 + ra1f2) : NINF;  // rule1 hop1
        lw2[bf]                 = msk ? -0.5f * (rh01 + ra2f2) : NINF;  // rule0 hop2
        lw2[(size_t)B * F + bf] = msk ? -0.5f * (rh11 + ra2f1) : NINF;  // rule1 hop2
        s0log[bf] = msk ? -0.5f * (rrel + ra1f1 + ra2f2) : NINF;        // scores_0
    }
}

// out[b] = exp(max_f s0log[b][f])
__global__ void k_s0red(const float* __restrict__ s0log, float* __restrict__ out,
                        int B, int F) {
    int b = blockIdx.x;
    int tid = threadIdx.x, lane = tid & 63, wave = tid >> 6;
    float m = NINF;
    for (int f = tid; f < F; f += 256) m = fmaxf(m, s0log[(size_t)b * F + f]);
    m = wmax(m);
    __shared__ float red[4];
    if (lane == 0) red[wave] = m;
    __syncthreads();
    if (tid == 0) out[b] = expf(fmaxf(fmaxf(red[0], red[1]), fmaxf(red[2], red[3])));
}

// hop1 via bf16 MFMA, double-buffered prefetch, log-space epilogue.
// nsc_part[y][r][b][n] = max over this f-tile of (lw1 - 0.5*relu(ne+nf-2*dot))
__global__ __launch_bounds__(256) void k_hop1m(
    const unsigned short* __restrict__ entb, const unsigned short* __restrict__ fa1b,
    const unsigned short* __restrict__ fa2b, const float* __restrict__ nf1,
    const float* __restrict__ nf2, const float* __restrict__ ne,
    const float* __restrict__ lw1, float* __restrict__ nsc_part, int B, int N, int F) {
    int z = blockIdx.z;
    int r = z / B, b = z % B;
    int BR = blockIdx.x * 128;  // entity rows
    int CB = blockIdx.y * 128;  // fact cols
    const unsigned short* factb = (r == 0) ? fa2b : fa1b;
    const float* nfp = (r == 0) ? nf2 : nf1;
    const float* w = lw1 + ((size_t)r * B + b) * F;
    const float* nep = ne + (size_t)b * N;

    __shared__ unsigned short ldsA[2 * 4096];  // 2 x 8 KB
    __shared__ unsigned short ldsB[2 * 4096];
    __shared__ float cmb[4][64];

    int tid = threadIdx.x, lane = tid & 63, wave = tid >> 6;
    int Rw = (wave >> 1) * 64, Cw = (wave & 1) * 64;
    int lr = lane & 15, lk = lane >> 4;

    const unsigned short* Ab = entb + ((size_t)b * N + BR) * E;
    const unsigned short* Bb = factb + ((size_t)b * F + CB) * E;

    f32x4 acc[4][4];
#pragma unroll
    for (int m = 0; m < 4; ++m)
#pragma unroll
        for (int n = 0; n < 4; ++n)
#pragma unroll
            for (int j = 0; j < 4; ++j) acc[m][n][j] = 0.0f;

#define STAGE(buf, kb)                                                        \
    {                                                                         \
        int k0 = (kb) * 32;                                                   \
        _Pragma("unroll") for (int is = 0; is < 2; ++is) {                    \
            int sbase = is * 256 + wave * 64;                                 \
            int sl = sbase + lane;                                            \
            int row = sl & 127, ko = sl >> 7;                                 \
            GLD16(Ab + (size_t)row * E + k0 + ko * 8,                         \
                  &ldsA[(buf) * 4096 + sbase * 8]);                           \
            GLD16(Bb + (size_t)row * E + k0 + ko * 8,                         \
                  &ldsB[(buf) * 4096 + sbase * 8]);                           \
        }                                                                     \
    }

    STAGE(0, 0);
    __syncthreads();  // prologue stage landed
#pragma unroll
    for (int kb = 0; kb < 8; ++kb) {
        int cur = kb & 1;
        if (kb + 1 < 8) STAGE(cur ^ 1, kb + 1);  // prefetch next K-step
        bf16x8 af[4], bfr[4];
#pragma unroll
        for (int m = 0; m < 4; ++m)
            af[m] = *(const bf16x8*)&ldsA[cur * 4096 +
                                          (lk * 128 + Rw + m * 16 + lr) * 8];
#pragma unroll
        for (int n = 0; n < 4; ++n)
            bfr[n] = *(const bf16x8*)&ldsB[cur * 4096 +
                                           (lk * 128 + Cw + n * 16 + lr) * 8];
#pragma unroll
        for (int m = 0; m < 4; ++m)
#pragma unroll
            for (int n = 0; n < 4; ++n)
                acc[m][n] = __builtin_amdgcn_mfma_f32_16x16x32_bf16(af[m], bfr[n],
                                                                    acc[m][n], 0, 0, 0);
        __syncthreads();  // drains vmcnt(0): prefetch complete, reads done
    }
#undef STAGE

    // epilogue (log space): val = min(acc + g(f) + h(n), lw(f)); max over f
    float nh[4][4];
#pragma unroll
    for (int m = 0; m < 4; ++m)
#pragma unroll
        for (int j = 0; j < 4; ++j)
            nh[m][j] = -0.5f * nep[BR + Rw + m * 16 + lk * 4 + j];
    float vmax[4][4];
#pragma unroll
    for (int m = 0; m < 4; ++m)
#pragma unroll
        for (int j = 0; j < 4; ++j) vmax[m][j] = NINF;
#pragma unroll
    for (int nfr = 0; nfr < 4; ++nfr) {
        int f = CB + Cw + nfr * 16 + lr;
        float lwf = w[f];
        float gf = fmaf(-0.5f, nfp[(size_t)b * F + f], lwf);
#pragma unroll
        for (int m = 0; m < 4; ++m)
#pragma unroll
            for (int j = 0; j < 4; ++j) {
                float t = (acc[m][nfr][j] + gf) + nh[m][j];
                vmax[m][j] = fmaxf(vmax[m][j], fminf(t, lwf));
            }
    }
    // reduce over the 16 lr lanes (different f, same rows)
#pragma unroll
    for (int m = 0; m < 4; ++m)
#pragma unroll
        for (int j = 0; j < 4; ++j) {
            float v = vmax[m][j];
            v = fmaxf(v, __shfl_xor(v, 1, 64));
            v = fmaxf(v, __shfl_xor(v, 2, 64));
            v = fmaxf(v, __shfl_xor(v, 4, 64));
            v = fmaxf(v, __shfl_xor(v, 8, 64));
            if (lr == 0) cmb[wave][m * 16 + lk * 4 + j] = v;
        }
    __syncthreads();
    // combine wave pairs (same rows, different f halves), direct store
    if (tid < 128) {
        int half = tid >> 6, rr = tid & 63;
        float v = fmaxf(cmb[half * 2][rr], cmb[half * 2 + 1][rr]);
        nsc_part[(size_t)blockIdx.y * (2 * (size_t)B * N) +
                 ((size_t)r * B + b) * N + BR + half * 64 + rr] = v;
    }
}

// top-10 per (r,b): fold f-tile partials, exp to value space, select with
// jax.lax.top_k tie-breaking (lower index wins on equal value)
__global__ void k_topk(const float* __restrict__ nsc_part, float* __restrict__ zval,
                       int* __restrict__ zidx, int B, int N, int NY) {
    int b = blockIdx.x, r = blockIdx.y;
    int tid = threadIdx.x;
    extern __shared__ float sv[];  // N floats
    size_t rbN = ((size_t)r * B + b) * N;
    for (int i = tid; i < N; i += 256) {
        float m = NINF;
        for (int y = 0; y < NY; ++y)
            m = fmaxf(m, nsc_part[(size_t)y * (2 * (size_t)B * N) + rbN + i]);
        sv[i] = expf(m);
    }
    __syncthreads();
    __shared__ float rv[256];
    __shared__ int ri[256];
    for (int t = 0; t < KTOP; ++t) {
        float bv = -1.f;
        int bi = 0;
        for (int i = tid; i < N; i += 256) {
            float v = sv[i];
            if (v > bv || (v == bv && i < bi)) { bv = v; bi = i; }
        }
        rv[tid] = bv; ri[tid] = bi;
        __syncthreads();
        for (int s = 128; s > 0; s >>= 1) {
            if (tid < s) {
                float v2 = rv[tid + s]; int i2 = ri[tid + s];
                if (v2 > rv[tid] || (v2 == rv[tid] && i2 < ri[tid])) {
                    rv[tid] = v2; ri[tid] = i2;
                }
            }
            __syncthreads();
        }
        if (tid == 0) {
            zval[((size_t)r * B + b) * KTOP + t] = rv[0];
            zidx[((size_t)r * B + b) * KTOP + t] = ri[0];
            sv[ri[0]] = -2.f;  // remove; all real values are >= 0
        }
        __syncthreads();
    }
}

// hop2 partial (log space): f-chunked max for the 10 selected sources per (r,b)
__global__ __launch_bounds__(256) void k_hop2p(
    const float* __restrict__ ent, const float* __restrict__ fa1,
    const float* __restrict__ fa2, const float* __restrict__ nf1,
    const float* __restrict__ nf2, const float* __restrict__ ne,
    const float* __restrict__ lw2, const int* __restrict__ zidx,
    float* __restrict__ h2part, int B, int N, int F) {
    int k = blockIdx.x, b = blockIdx.y;
    int rc = blockIdx.z;
    int r = rc >> 3, c = rc & (H2CH - 1);
    const float* fact = (r == 0) ? fa1 : fa2;  // r0: src vs fact_arg1; r1: src vs fact_arg2
    const float* nf = (r == 0) ? nf1 : nf2;
    int tid = threadIdx.x, lane = tid & 63, wave = tid >> 6;
    int idx = zidx[((size_t)r * B + b) * KTOP + k];
    float4 q = ((const float4*)(ent + ((size_t)b * N + idx) * E))[lane];
    float nsrc = ne[(size_t)b * N + idx];
    int fchunk = F / H2CH;
    int fbeg = c * fchunk, fend = fbeg + fchunk;
    float vmax = NINF;
    for (int f = fbeg + wave; f < fend; f += 4) {
        float4 v = ((const float4*)(fact + ((size_t)b * F + f) * E))[lane];
        float d = wsum(dot4(v, q));
        float lwf = lw2[(size_t)r * B * F + (size_t)b * F + f];
        float g = lwf - 0.5f * (nf[(size_t)b * F + f] + nsrc);
        vmax = fmaxf(vmax, fminf(d + g, lwf));
    }
    __shared__ float red[4];
    if (lane == 0) red[wave] = vmax;
    __syncthreads();
    if (tid == 0) {
        float z2 = fmaxf(fmaxf(red[0], red[1]), fmaxf(red[2], red[3]));
        h2part[(((size_t)r * B + b) * KTOP + k) * H2CH + c] = z2;
    }
}

// combine: out[b] = max(out[b], min(exp(max_c h2part), zval)) over all (r,k)
__global__ void k_hop2c(const float* __restrict__ h2part, const float* __restrict__ zval,
                        float* __restrict__ out, int B) {
    int i = blockIdx.x * 256 + threadIdx.x;
    int n = 2 * B * KTOP;
    if (i < n) {
        int b = (i / KTOP) % B;
        float m = NINF;
#pragma unroll
        for (int c = 0; c < H2CH; ++c) m = fmaxf(m, h2part[(size_t)i * H2CH + c]);
        float sc = fminf(expf(m), zval[i]);
        atomicMaxF(&out[b], sc);
    }
}

// ---------- launcher ----------
extern "C" void kernel_launch(void* const* d_in, const int* in_sizes, int n_in,
                              void* d_out, int out_size, void* d_ws, size_t ws_size,
                              hipStream_t stream) {
    const float* rel = (const float*)d_in[0];
    const float* arg1 = (const float*)d_in[1];
    const float* arg2 = (const float*)d_in[2];
    const float* frel = (const float*)d_in[3];
    const float* fa1 = (const float*)d_in[4];
    const float* fa2 = (const float*)d_in[5];
    const int* nbf = (const int*)d_in[6];
    const float* ent = (const float*)d_in[7];
    const float* W = (const float*)d_in[9];
    const float* bias = (const float*)d_in[10];
    int B = in_sizes[0] / E;
    int F = in_sizes[3] / (B * E);
    int N = in_sizes[7] / (B * E);
    int NY = F / 128;
    float* out = (float*)d_out;

    float* ws = (float*)d_ws;
    size_t o = 0;
    float* hr = ws + o;   o += (size_t)4 * B * E;
    float* nhr = ws + o;  o += (size_t)4 * B;
    float* nrel = ws + o; o += B;
    float* na1 = ws + o;  o += B;
    float* na2 = ws + o;  o += B;
    float* nf1 = ws + o;  o += (size_t)B * F;
    float* nf2 = ws + o;  o += (size_t)B * F;
    float* ne_ = ws + o;  o += (size_t)B * N;
    float* lw1 = ws + o;  o += (size_t)2 * B * F;
    float* lw2 = ws + o;  o += (size_t)2 * B * F;
    float* zval = ws + o; o += (size_t)2 * B * KTOP;
    int* zidx = (int*)(ws + o); o += (size_t)2 * B * KTOP;
    float* s0log = ws + o; o += (size_t)B * F;
    float* h2part = ws + o; o += (size_t)2 * B * KTOP * H2CH;
    float* nsc_part = ws + o; o += (size_t)NY * 2 * B * N;
    unsigned short* fa1b = (unsigned short*)(ws + o); o += (size_t)B * F * E / 2;
    unsigned short* fa2b = (unsigned short*)(ws + o); o += (size_t)B * F * E / 2;
    unsigned short* entb = (unsigned short*)(ws + o); o += (size_t)B * N * E / 2;

    k_hoprel<<<dim3(B, 4), dim3(E), 0, stream>>>(rel, W, bias, hr, nhr, B);
    k_rownorm<<<dim3((B + 3) / 4), dim3(256), 0, stream>>>(rel, nrel, B);
    k_rownorm<<<dim3((B + 3) / 4), dim3(256), 0, stream>>>(arg1, na1, B);
    k_rownorm<<<dim3((B + 3) / 4), dim3(256), 0, stream>>>(arg2, na2, B);
    int totrows = 2 * B * F + B * N;
    k_prep<<<dim3((totrows + 3) / 4), dim3(256), 0, stream>>>(
        fa1, fa2, ent, fa1b, fa2b, entb, nf1, nf2, ne_, B * F, B * N);
    k_pairmap<<<dim3(F / 4, B), dim3(256), 0, stream>>>(
        rel, arg1, arg2, frel, fa1, fa2, nbf, hr, nhr, nrel, na1, na2, lw1, lw2, nf1,
        nf2, s0log, B, F);
    k_s0red<<<dim3(B), dim3(256), 0, stream>>>(s0log, out, B, F);
    k_hop1m<<<dim3(N / 128, NY, 2 * B), dim3(256), 0, stream>>>(
        entb, fa1b, fa2b, nf1, nf2, ne_, lw1, nsc_part, B, N, F);
    k_topk<<<dim3(B, 2), dim3(256), N * sizeof(float), stream>>>(nsc_part, zval, zidx,
                                                                 B, N, NY);
    k_hop2p<<<dim3(KTOP, B, 2 * H2CH), dim3(256), 0, stream>>>(
        ent, fa1, fa2, nf1, nf2, ne_, lw2, zidx, h2part, B, N, F);
    k_hop2c<<<dim3((2 * B * KTOP + 255) / 256), dim3(256), 0, stream>>>(h2part, zval,
                                                                        out, B);
}

// Round 5
// 206.019 us; speedup vs baseline: 6.2419x; 1.4144x over previous
//
#include <hip/hip_runtime.h>
#include <math.h>

#define E 256
#define KTOP 10
#define H2C 8
#define NINF (-__builtin_huge_valf())

typedef __attribute__((ext_vector_type(8))) short bf16x8;
typedef __attribute__((ext_vector_type(4))) float f32x4;

// ---------- helpers ----------
__device__ inline float wsum(float v) {
    v += __shfl_xor(v, 1, 64);
    v += __shfl_xor(v, 2, 64);
    v += __shfl_xor(v, 4, 64);
    v += __shfl_xor(v, 8, 64);
    v += __shfl_xor(v, 16, 64);
    v += __shfl_xor(v, 32, 64);
    return v;
}

__device__ inline float wmax(float v) {
    v = fmaxf(v, __shfl_xor(v, 1, 64));
    v = fmaxf(v, __shfl_xor(v, 2, 64));
    v = fmaxf(v, __shfl_xor(v, 4, 64));
    v = fmaxf(v, __shfl_xor(v, 8, 64));
    v = fmaxf(v, __shfl_xor(v, 16, 64));
    v = fmaxf(v, __shfl_xor(v, 32, 64));
    return v;
}

__device__ inline float dot4(float4 a, float4 b) {
    return a.x * b.x + a.y * b.y + a.z * b.z + a.w * b.w;
}

__device__ inline void atomicMaxF(float* addr, float v) {
    atomicMax((unsigned int*)addr, __float_as_uint(v));  // non-negative floats
}

__device__ inline unsigned short f2bf(float x) {  // RNE f32 -> bf16
    unsigned u = __float_as_uint(x);
    unsigned r = (u + 0x7FFFu + ((u >> 16) & 1u)) >> 16;
    return (unsigned short)r;
}

// ---------- kernels ----------
// hop_rel rows + all small norms (rel/arg1/arg2 + hop_rel norms)
__global__ void k_hoprel(const float* __restrict__ rel, const float* __restrict__ arg1,
                         const float* __restrict__ arg2, const float* __restrict__ W,
                         const float* __restrict__ bias, float* __restrict__ hr,
                         float* __restrict__ nhr, float* __restrict__ nrel,
                         float* __restrict__ na1, float* __restrict__ na2, int B) {
    int b = blockIdx.x, rh = blockIdx.y;
    int j = threadIdx.x;  // 0..255
    __shared__ float relS[E];
    __shared__ float red[4];
    __shared__ float red2[4];
    relS[j] = rel[b * E + j];
    __syncthreads();
    const float* Wp = W + (size_t)rh * E * E;
    float acc = bias[rh * E + j];
#pragma unroll 8
    for (int e = 0; e < E; ++e) acc = fmaf(relS[e], Wp[e * E + j], acc);
    hr[((size_t)rh * B + b) * E + j] = acc;
    float s = wsum(acc * acc);
    int wave = j >> 6;
    if ((j & 63) == 0) red[wave] = s;
    // small norms: rh 0/1/2 -> rel/arg1/arg2
    float x = 0.f;
    if (rh == 0) x = relS[j];
    else if (rh == 1) x = arg1[b * E + j];
    else if (rh == 2) x = arg2[b * E + j];
    float s2 = wsum(x * x);
    if ((j & 63) == 0) red2[wave] = s2;
    __syncthreads();
    if (j == 0) {
        nhr[rh * B + b] = red[0] + red[1] + red[2] + red[3];
        if (rh < 3) {
            float nv = red2[0] + red2[1] + red2[2] + red2[3];
            (rh == 0 ? nrel : (rh == 1 ? na1 : na2))[b] = nv;
        }
    }
}

// ent: norms + bf16
__global__ void k_prep_ent(const float* __restrict__ ent, unsigned short* __restrict__ entb,
                           float* __restrict__ ne_, int BN) {
    int row = blockIdx.x * 4 + (threadIdx.x >> 6);
    if (row >= BN) return;
    int lane = threadIdx.x & 63;
    float4 v = ((const float4*)(ent + (size_t)row * E))[lane];
    float s = wsum(dot4(v, v));
    if (lane == 0) ne_[row] = s;
    ushort4 o;
    o.x = f2bf(v.x); o.y = f2bf(v.y); o.z = f2bf(v.z); o.w = f2bf(v.w);
    ((ushort4*)(entb + (size_t)row * E))[lane] = o;
}

// single pass over facts: norms, bf16 casts, log-space weights, s0log
__global__ __launch_bounds__(256) void k_fused(
    const float* __restrict__ rel, const float* __restrict__ arg1,
    const float* __restrict__ arg2, const float* __restrict__ frel,
    const float* __restrict__ fa1, const float* __restrict__ fa2,
    const int* __restrict__ nbf, const float* __restrict__ hr,
    const float* __restrict__ nhr, const float* __restrict__ nrel,
    const float* __restrict__ na1, const float* __restrict__ na2,
    float* __restrict__ lw1, float* __restrict__ lw2, float* __restrict__ s0log,
    float* __restrict__ nf1, float* __restrict__ nf2,
    unsigned short* __restrict__ fa1b, unsigned short* __restrict__ fa2b,
    int B, int F) {
    int b = blockIdx.y;
    int lane = threadIdx.x & 63, wave = threadIdx.x >> 6;
    int f = blockIdx.x * 4 + wave;
    size_t bf = (size_t)b * F + f;
    float4 qrel = ((const float4*)(rel + (size_t)b * E))[lane];
    float4 qa1  = ((const float4*)(arg1 + (size_t)b * E))[lane];
    float4 qa2  = ((const float4*)(arg2 + (size_t)b * E))[lane];
    float4 qh00 = ((const float4*)(hr + ((size_t)0 * B + b) * E))[lane];
    float4 qh01 = ((const float4*)(hr + ((size_t)1 * B + b) * E))[lane];
    float4 qh10 = ((const float4*)(hr + ((size_t)2 * B + b) * E))[lane];
    float4 qh11 = ((const float4*)(hr + ((size_t)3 * B + b) * E))[lane];
    float4 v  = ((const float4*)(frel + bf * E))[lane];
    float4 v1 = ((const float4*)(fa1 + bf * E))[lane];
    float4 v2 = ((const float4*)(fa2 + bf * E))[lane];
    // bf16 casts
    ushort4 o1, o2;
    o1.x = f2bf(v1.x); o1.y = f2bf(v1.y); o1.z = f2bf(v1.z); o1.w = f2bf(v1.w);
    o2.x = f2bf(v2.x); o2.y = f2bf(v2.y); o2.z = f2bf(v2.z); o2.w = f2bf(v2.w);
    ((ushort4*)(fa1b + bf * E))[lane] = o1;
    ((ushort4*)(fa2b + bf * E))[lane] = o2;
    // 12 reductions
    float d_rel  = wsum(dot4(v, qrel));
    float d_h00  = wsum(dot4(v, qh00));
    float d_h01  = wsum(dot4(v, qh01));
    float d_h10  = wsum(dot4(v, qh10));
    float d_h11  = wsum(dot4(v, qh11));
    float n_fr   = wsum(dot4(v, v));
    float d_a1f1 = wsum(dot4(v1, qa1));
    float d_a2f1 = wsum(dot4(v1, qa2));
    float n_f1   = wsum(dot4(v1, v1));
    float d_a1f2 = wsum(dot4(v2, qa1));
    float d_a2f2 = wsum(dot4(v2, qa2));
    float n_f2   = wsum(dot4(v2, v2));
    if (lane == 0) {
        bool msk = (f < nbf[b]);
        float rrel  = fmaxf(nrel[b] + n_fr - 2.f * d_rel, 0.f);
        float rh00  = fmaxf(nhr[0 * B + b] + n_fr - 2.f * d_h00, 0.f);
        float rh01  = fmaxf(nhr[1 * B + b] + n_fr - 2.f * d_h01, 0.f);
        float rh10  = fmaxf(nhr[2 * B + b] + n_fr - 2.f * d_h10, 0.f);
        float rh11  = fmaxf(nhr[3 * B + b] + n_fr - 2.f * d_h11, 0.f);
        float ra1f1 = fmaxf(na1[b] + n_f1 - 2.f * d_a1f1, 0.f);
        float ra2f1 = fmaxf(na2[b] + n_f1 - 2.f * d_a2f1, 0.f);
        float ra1f2 = fmaxf(na1[b] + n_f2 - 2.f * d_a1f2, 0.f);
        float ra2f2 = fmaxf(na2[b] + n_f2 - 2.f * d_a2f2, 0.f);
        nf1[bf] = n_f1;
        nf2[bf] = n_f2;
        lw1[bf]                 = msk ? -0.5f * (rh00 + ra1f1) : NINF;
        lw1[(size_t)B * F + bf] = msk ? -0.5f * (rh10 + ra1f2) : NINF;
        lw2[bf]                 = msk ? -0.5f * (rh01 + ra2f2) : NINF;
        lw2[(size_t)B * F + bf] = msk ? -0.5f * (rh11 + ra2f1) : NINF;
        s0log[bf] = msk ? -0.5f * (rrel + ra1f1 + ra2f2) : NINF;
    }
}

// out[b] = exp(max_f s0log[b][f])
__global__ void k_s0red(const float* __restrict__ s0log, float* __restrict__ out,
                        int B, int F) {
    int b = blockIdx.x;
    int tid = threadIdx.x, lane = tid & 63, wave = tid >> 6;
    float m = NINF;
    for (int f = tid; f < F; f += 256) m = fmaxf(m, s0log[(size_t)b * F + f]);
    m = wmax(m);
    __shared__ float red[4];
    if (lane == 0) red[wave] = m;
    __syncthreads();
    if (tid == 0) out[b] = expf(fmaxf(fmaxf(red[0], red[1]), fmaxf(red[2], red[3])));
}

// hop1: A(ent) in registers, B(fact) fragments direct from global/L2. No LDS.
// Block: 128 ent rows x (r,b) x F-half. 4 waves x 32 rows (m=2). XCD-swizzled.
__global__ __launch_bounds__(256, 2) void k_hop1m(
    const unsigned short* __restrict__ entb, const unsigned short* __restrict__ fa1b,
    const unsigned short* __restrict__ fa2b, const float* __restrict__ nf1,
    const float* __restrict__ nf2, const float* __restrict__ ne,
    const float* __restrict__ lw1, float* __restrict__ nsc_part, int B, int N, int F) {
    // swizzle: all blocks of batch-pair {xcd, xcd+8} on one XCD
    int L = blockIdx.x;
    int xcd = L & 7, s = L >> 3;
    int b = ((s >> 5) << 3) | xcd;
    int inner = s & 31;
    int r = inner >> 4, fs = (inner >> 3) & 1, nb = inner & 7;
    int BR = nb * 128;
    int F0 = fs * (F / 2);
    const unsigned short* factb = (r == 0) ? fa2b : fa1b;
    const float* nfp = ((r == 0) ? nf2 : nf1) + (size_t)b * F;
    const float* w = lw1 + ((size_t)r * B + b) * F;
    const float* nep = ne + (size_t)b * N;

    int tid = threadIdx.x, lane = tid & 63, wave = tid >> 6;
    int lr = lane & 15, lk = lane >> 4;
    int row0 = BR + wave * 32;

    // A fragments: 2 m-frags x 8 k-steps, in registers
    const unsigned short* Ab = entb + (size_t)b * N * E;
    bf16x8 areg[2][8];
#pragma unroll
    for (int m = 0; m < 2; ++m)
#pragma unroll
        for (int kb = 0; kb < 8; ++kb)
            areg[m][kb] = *(const bf16x8*)(Ab + (size_t)(row0 + m * 16 + lr) * E +
                                           kb * 32 + lk * 8);
    float nh[2][4];
#pragma unroll
    for (int m = 0; m < 2; ++m)
#pragma unroll
        for (int j = 0; j < 4; ++j)
            nh[m][j] = -0.5f * nep[row0 + m * 16 + lk * 4 + j];

    float vmax[2][4];
#pragma unroll
    for (int m = 0; m < 2; ++m)
#pragma unroll
        for (int j = 0; j < 4; ++j) vmax[m][j] = NINF;

    const unsigned short* Bb = factb + ((size_t)b * F + F0) * E;
    for (int ft = 0; ft < F / 2 / 64; ++ft) {  // 16 tiles of 64 cols
#pragma unroll
        for (int n = 0; n < 4; ++n) {
            int fcol = F0 + ft * 64 + n * 16;
            bf16x8 bfr[8];
#pragma unroll
            for (int kb = 0; kb < 8; ++kb)
                bfr[kb] = *(const bf16x8*)(Bb + (size_t)(ft * 64 + n * 16 + lr) * E +
                                           kb * 32 + lk * 8);
            f32x4 acc0 = {0.f, 0.f, 0.f, 0.f}, acc1 = {0.f, 0.f, 0.f, 0.f};
#pragma unroll
            for (int kb = 0; kb < 8; ++kb) {
                acc0 = __builtin_amdgcn_mfma_f32_16x16x32_bf16(areg[0][kb], bfr[kb],
                                                               acc0, 0, 0, 0);
                acc1 = __builtin_amdgcn_mfma_f32_16x16x32_bf16(areg[1][kb], bfr[kb],
                                                               acc1, 0, 0, 0);
            }
            float lwf = w[fcol + lr];
            float gf = fmaf(-0.5f, nfp[fcol + lr], lwf);
#pragma unroll
            for (int j = 0; j < 4; ++j) {
                float t0 = acc0[j] + gf + nh[0][j];
                float t1 = acc1[j] + gf + nh[1][j];
                vmax[0][j] = fmaxf(vmax[0][j], fminf(t0, lwf));
                vmax[1][j] = fmaxf(vmax[1][j], fminf(t1, lwf));
            }
        }
    }
    // reduce over the 16 lr lanes; store partials (no atomics)
#pragma unroll
    for (int m = 0; m < 2; ++m)
#pragma unroll
        for (int j = 0; j < 4; ++j) {
            float v = vmax[m][j];
            v = fmaxf(v, __shfl_xor(v, 1, 64));
            v = fmaxf(v, __shfl_xor(v, 2, 64));
            v = fmaxf(v, __shfl_xor(v, 4, 64));
            v = fmaxf(v, __shfl_xor(v, 8, 64));
            if (lr == 0) {
                int row = row0 + m * 16 + lk * 4 + j;
                nsc_part[(size_t)fs * (2 * (size_t)B * N) +
                         ((size_t)r * B + b) * N + row] = v;
            }
        }
}

// top-10 per (r,b): fold partials, exp to value space, jax.lax.top_k tie-break
__global__ void k_topk(const float* __restrict__ nsc_part, float* __restrict__ zval,
                       int* __restrict__ zidx, int B, int N, int NY) {
    int b = blockIdx.x, r = blockIdx.y;
    int tid = threadIdx.x;
    extern __shared__ float sv[];  // N floats
    size_t rbN = ((size_t)r * B + b) * N;
    for (int i = tid; i < N; i += 256) {
        float m = NINF;
        for (int y = 0; y < NY; ++y)
            m = fmaxf(m, nsc_part[(size_t)y * (2 * (size_t)B * N) + rbN + i]);
        sv[i] = expf(m);
    }
    __syncthreads();
    __shared__ float rv[256];
    __shared__ int ri[256];
    for (int t = 0; t < KTOP; ++t) {
        float bv = -1.f;
        int bi = 0;
        for (int i = tid; i < N; i += 256) {
            float v = sv[i];
            if (v > bv || (v == bv && i < bi)) { bv = v; bi = i; }
        }
        rv[tid] = bv; ri[tid] = bi;
        __syncthreads();
        for (int s = 128; s > 0; s >>= 1) {
            if (tid < s) {
                float v2 = rv[tid + s]; int i2 = ri[tid + s];
                if (v2 > rv[tid] || (v2 == rv[tid] && i2 < ri[tid])) {
                    rv[tid] = v2; ri[tid] = i2;
                }
            }
            __syncthreads();
        }
        if (tid == 0) {
            zval[((size_t)r * B + b) * KTOP + t] = rv[0];
            zidx[((size_t)r * B + b) * KTOP + t] = ri[0];
            sv[ri[0]] = -2.f;
        }
        __syncthreads();
    }
}

// hop2 via MFMA: 10 gathered sources (A, LDS-staged once) vs fact cols (B, direct).
__global__ __launch_bounds__(256) void k_hop2m(
    const unsigned short* __restrict__ entb, const unsigned short* __restrict__ fa1b,
    const unsigned short* __restrict__ fa2b, const float* __restrict__ nf1,
    const float* __restrict__ nf2, const float* __restrict__ ne,
    const float* __restrict__ lw2, const int* __restrict__ zidx,
    float* __restrict__ h2part, int B, int N, int F) {
    int L = blockIdx.x;
    int xcd = L & 7, s = L >> 3;
    int b = ((s >> 4) << 3) | xcd;
    int inner = s & 15;
    int r = inner >> 3, c = inner & 7;
    const unsigned short* factb = (r == 0) ? fa1b : fa2b;
    const float* nfp = ((r == 0) ? nf1 : nf2) + (size_t)b * F;
    const float* w = lw2 + ((size_t)r * B + b) * F;
    int tid = threadIdx.x, lane = tid & 63, wave = tid >> 6;
    int lr = lane & 15, lk = lane >> 4;
    __shared__ unsigned short aLds[32 * 16 * 8];  // [kchunk][row16][8] = 8KB
    __shared__ float snrm[16];
    for (int ci = tid; ci < 512; ci += 256) {
        int row = ci & 15, kc = ci >> 4;
        ushort4 v0 = {0, 0, 0, 0}, v1 = {0, 0, 0, 0};
        if (row < KTOP) {
            int idx = zidx[((size_t)r * B + b) * KTOP + row];
            const unsigned short* src = entb + ((size_t)b * N + idx) * E + kc * 8;
            v0 = *(const ushort4*)src;
            v1 = *(const ushort4*)(src + 4);
        }
        *(ushort4*)&aLds[(size_t)ci * 8] = v0;
        *(ushort4*)&aLds[(size_t)ci * 8 + 4] = v1;
    }
    if (tid < 16) {
        float nv = 0.f;
        if (tid < KTOP) {
            int idx = zidx[((size_t)r * B + b) * KTOP + tid];
            nv = ne[(size_t)b * N + idx];
        }
        snrm[tid] = nv;
    }
    __syncthreads();
    bf16x8 afr[8];
#pragma unroll
    for (int kb = 0; kb < 8; ++kb)
        afr[kb] = *(const bf16x8*)&aLds[((kb * 4 + lk) * 16 + lr) * 8];
    float nhs[4];
#pragma unroll
    for (int j = 0; j < 4; ++j) nhs[j] = -0.5f * snrm[lk * 4 + j];
    int fchunk = F / H2C;                          // 256
    int fbase = c * fchunk + wave * (fchunk / 4);  // wave's 64 cols
    float vmax[4] = {NINF, NINF, NINF, NINF};
    const unsigned short* Bb = factb + (size_t)b * F * E;
#pragma unroll
    for (int n = 0; n < 4; ++n) {
        int fcol = fbase + n * 16;
        bf16x8 bfr[8];
#pragma unroll
        for (int kb = 0; kb < 8; ++kb)
            bfr[kb] = *(const bf16x8*)(Bb + (size_t)(fcol + lr) * E + kb * 32 + lk * 8);
        f32x4 acc = {0.f, 0.f, 0.f, 0.f};
#pragma unroll
        for (int kb = 0; kb < 8; ++kb)
            acc = __builtin_amdgcn_mfma_f32_16x16x32_bf16(afr[kb], bfr[kb], acc, 0, 0, 0);
        float lwf = w[fcol + lr];
        float gf = fmaf(-0.5f, nfp[fcol + lr], lwf);
#pragma unroll
        for (int j = 0; j < 4; ++j) {
            float t = acc[j] + gf + nhs[j];
            vmax[j] = fmaxf(vmax[j], fminf(t, lwf));
        }
    }
#pragma unroll
    for (int j = 0; j < 4; ++j) {
        float v = vmax[j];
        v = fmaxf(v, __shfl_xor(v, 1, 64));
        v = fmaxf(v, __shfl_xor(v, 2, 64));
        v = fmaxf(v, __shfl_xor(v, 4, 64));
        v = fmaxf(v, __shfl_xor(v, 8, 64));
        int sidx = lk * 4 + j;
        if (lr == 0 && sidx < KTOP)
            h2part[(((size_t)r * B + b) * KTOP + sidx) * 32 + c * 4 + wave] = v;
    }
}

// combine: out[b] = max(out[b], min(exp(max_c h2part), zval))
__global__ void k_hop2c(const float* __restrict__ h2part, const float* __restrict__ zval,
                        float* __restrict__ out, int B) {
    int i = blockIdx.x * 256 + threadIdx.x;
    int n = 2 * B * KTOP;
    if (i < n) {
        int b = (i / KTOP) % B;
        float m = NINF;
#pragma unroll
        for (int c2 = 0; c2 < 32; ++c2) m = fmaxf(m, h2part[(size_t)i * 32 + c2]);
        float sc = fminf(expf(m), zval[i]);
        atomicMaxF(&out[b], sc);
    }
}

// ---------- launcher ----------
extern "C" void kernel_launch(void* const* d_in, const int* in_sizes, int n_in,
                              void* d_out, int out_size, void* d_ws, size_t ws_size,
                              hipStream_t stream) {
    const float* rel = (const float*)d_in[0];
    const float* arg1 = (const float*)d_in[1];
    const float* arg2 = (const float*)d_in[2];
    const float* frel = (const float*)d_in[3];
    const float* fa1 = (const float*)d_in[4];
    const float* fa2 = (const float*)d_in[5];
    const int* nbf = (const int*)d_in[6];
    const float* ent = (const float*)d_in[7];
    const float* W = (const float*)d_in[9];
    const float* bias = (const float*)d_in[10];
    int B = in_sizes[0] / E;
    int F = in_sizes[3] / (B * E);
    int N = in_sizes[7] / (B * E);
    int NY = 2;
    float* out = (float*)d_out;

    float* ws = (float*)d_ws;
    size_t o = 0;
    float* hr = ws + o;   o += (size_t)4 * B * E;
    float* nhr = ws + o;  o += (size_t)4 * B;
    float* nrel = ws + o; o += B;
    float* na1 = ws + o;  o += B;
    float* na2 = ws + o;  o += B * 2;  // keep 16B alignment
    float* nf1 = ws + o;  o += (size_t)B * F;
    float* nf2 = ws + o;  o += (size_t)B * F;
    float* ne_ = ws + o;  o += (size_t)B * N;
    float* lw1 = ws + o;  o += (size_t)2 * B * F;
    float* lw2 = ws + o;  o += (size_t)2 * B * F;
    float* zval = ws + o; o += (size_t)2 * B * KTOP;
    int* zidx = (int*)(ws + o); o += (size_t)2 * B * KTOP;
    float* s0log = ws + o; o += (size_t)B * F;
    float* h2part = ws + o; o += (size_t)2 * B * KTOP * 32;
    float* nsc_part = ws + o; o += (size_t)NY * 2 * B * N;
    unsigned short* fa1b = (unsigned short*)(ws + o); o += (size_t)B * F * E / 2;
    unsigned short* fa2b = (unsigned short*)(ws + o); o += (size_t)B * F * E / 2;
    unsigned short* entb = (unsigned short*)(ws + o); o += (size_t)B * N * E / 2;

    k_hoprel<<<dim3(B, 4), dim3(E), 0, stream>>>(rel, arg1, arg2, W, bias, hr, nhr,
                                                 nrel, na1, na2, B);
    k_prep_ent<<<dim3((B * N + 3) / 4), dim3(256), 0, stream>>>(ent, entb, ne_, B * N);
    k_fused<<<dim3(F / 4, B), dim3(256), 0, stream>>>(
        rel, arg1, arg2, frel, fa1, fa2, nbf, hr, nhr, nrel, na1, na2, lw1, lw2,
        s0log, nf1, nf2, fa1b, fa2b, B, F);
    k_s0red<<<dim3(B), dim3(256), 0, stream>>>(s0log, out, B, F);
    k_hop1m<<<dim3(512), dim3(256), 0, stream>>>(entb, fa1b, fa2b, nf1, nf2, ne_, lw1,
                                                 nsc_part, B, N, F);
    k_topk<<<dim3(B, 2), dim3(256), N * sizeof(float), stream>>>(nsc_part, zval, zidx,
                                                                 B, N, NY);
    k_hop2m<<<dim3(256), dim3(256), 0, stream>>>(entb, fa1b, fa2b, nf1, nf2, ne_, lw2,
                                                 zidx, h2part, B, N, F);
    k_hop2c<<<dim3((2 * B * KTOP + 255) / 256), dim3(256), 0, stream>>>(h2part, zval,
                                                                        out, B);
}